// Round 2
// baseline (8870.123 us; speedup 1.0000x reference)
//
#include <hip/hip_runtime.h>
#include <hip/hip_bf16.h>
#include <stdint.h>

// EncoderFLAX: x = emb[inputs]; xW = x@Wi + b; LSTM scan over S with Wh.
// B=256 S=256 V=32000 E=1024 H=1024. Outputs: [B,S,H] fp32, h [B,H], c [B,H].
//
// Round 2 changes:
//  - lstm scan: ONE persistent kernel (256 blocks x 512 thr, 1 block/CU),
//    device-scope sense-free barrier between steps (monotonic counter,
//    RELEASE add + ACQUIRE spin at AGENT scope for cross-XCD visibility).
//    c-state kept in registers across all 256 steps (no cst HBM traffic);
//    XW cell inputs prefetched into regs before the MFMA phase (T14).
//  - gemm_xw epilogue: C-tile staged through padded LDS [64][136] then
//    written with coalesced uint4 stores (was: scattered 2B bf16 stores).
//
// ws layout (bytes):
//   WiT 0..8388608, WhT ..16777216, hb0 ..17301504, hb1 ..17825792,
//   X ..152043520, XW ..688914432
// barrier counter lives in d_out's h-output region (only written at t=255,
// after the last barrier use; re-zeroed by zero_init each launch).

#define B_ 256
#define S_ 256
#define E_ 1024
#define H_ 1024
#define G_ 4096
#define M_ 65536

typedef float  f32x4  __attribute__((ext_vector_type(4)));
typedef __bf16 bf16x8 __attribute__((ext_vector_type(8)));
typedef __bf16 bf16x2 __attribute__((ext_vector_type(2)));

#define MFMA16(a, b, c) __builtin_amdgcn_mfma_f32_16x16x32_bf16((a), (b), (c), 0, 0, 0)

__device__ __forceinline__ void gload_lds16(const void* g, void* l) {
  __builtin_amdgcn_global_load_lds(
      (__attribute__((address_space(1))) void*)(g),
      (__attribute__((address_space(3))) void*)(l), 16, 0, 0);
}

__device__ __forceinline__ float sigm(float x) { return 1.f / (1.f + __expf(-x)); }
__device__ __forceinline__ float tanhfast(float x) {
  float e = __expf(-2.f * x);
  return (1.f - e) / (1.f + e);
}
__device__ __forceinline__ float bf_lo(unsigned v) { return __uint_as_float(v << 16); }
__device__ __forceinline__ float bf_hi(unsigned v) { return __uint_as_float(v & 0xffff0000u); }

// ---------------------------------------------------------------- zero init
__global__ __launch_bounds__(256) void zero_init(uint4* h16, unsigned* bar) {
  int i = blockIdx.x * 256 + threadIdx.x;
  if (i == 0) *bar = 0u;
  uint4 z; z.x = z.y = z.z = z.w = 0u;
  if (i < 32768) h16[i] = z;            // hb0: 262144 bf16 = 32768 x 16B
}

// ------------------------------------------------- transpose+cast [1024][4096]
__global__ __launch_bounds__(256) void transpose_cast(const float* __restrict__ in,
                                                      __bf16* __restrict__ out) {
  __shared__ __bf16 tile[32][33];
  const int c0 = blockIdx.x * 32;
  const int r0 = blockIdx.y * 32;
  const int tx = threadIdx.x & 31, ty = threadIdx.x >> 5;
#pragma unroll
  for (int p = 0; p < 4; ++p) {
    const int rr = ty + p * 8;
    tile[rr][tx] = (__bf16)in[(size_t)(r0 + rr) * G_ + c0 + tx];
  }
  __syncthreads();
#pragma unroll
  for (int p = 0; p < 4; ++p) {
    const int rr = ty + p * 8;
    out[(size_t)(c0 + rr) * E_ + r0 + tx] = tile[tx][rr];
  }
}

// ------------------------------------------------------- embedding gather+cast
union U16b { uint4 v; __bf16 h[8]; };
__global__ __launch_bounds__(256) void gather_cast(const int* __restrict__ idx,
                                                   const float* __restrict__ emb,
                                                   __bf16* __restrict__ X) {
  const size_t gid  = (size_t)blockIdx.x * 256 + threadIdx.x;
  const size_t base = gid * 8;
  const int r = (int)(base >> 10);
  const int e = (int)(base & 1023);
  const int row = idx[r];
  const float4* s = (const float4*)(emb + (size_t)row * E_ + e);
  const float4 v0 = s[0], v1 = s[1];
  U16b u;
  u.h[0] = (__bf16)v0.x; u.h[1] = (__bf16)v0.y; u.h[2] = (__bf16)v0.z; u.h[3] = (__bf16)v0.w;
  u.h[4] = (__bf16)v1.x; u.h[5] = (__bf16)v1.y; u.h[6] = (__bf16)v1.z; u.h[7] = (__bf16)v1.w;
  *(uint4*)(X + base) = u.v;
}

// --------------------------------------------------- xW GEMM (m97 structure)
// C[65536,4096] = X @ WiT^T + bias. Epilogue: LDS re-layout -> uint4 stores.
__global__ __launch_bounds__(256) void gemm_xw(const __bf16* __restrict__ X,
                                               const __bf16* __restrict__ WiT,
                                               const float* __restrict__ bias,
                                               __bf16* __restrict__ XW) {
  __shared__ __bf16 As[128 * 32];
  __shared__ __bf16 Bs[128 * 32];
  __shared__ __bf16 eps[64][136];       // padded epilogue staging (2-way-free)
  const int tid = threadIdx.x;
  const int lane = tid & 63;
  const int wid = tid >> 6;
  const int bn = blockIdx.x & 31;
  const int bm = blockIdx.x >> 5;
  const int row0 = bm * 128, col0 = bn * 128;
  const int wr = (wid >> 1) * 64, wc = (wid & 1) * 64;
  const int srow = tid >> 2, schunk = tid & 3;
  const char* gA = (const char*)(X + (size_t)(row0 + srow) * E_) + schunk * 16;
  const char* gB = (const char*)(WiT + (size_t)(col0 + srow) * E_) + schunk * 16;
  char* lA = (char*)As + wid * 1024;
  char* lB = (char*)Bs + wid * 1024;
  const int fr = lane & 15, kb = lane >> 4;

  f32x4 acc[4][4] = {};

  for (int kt = 0; kt < 32; ++kt) {
    gload_lds16(gA + kt * 64,              lA);
    gload_lds16(gA + kt * 64 + 64 * 2048,  lA + 4096);
    gload_lds16(gB + kt * 64,              lB);
    gload_lds16(gB + kt * 64 + 64 * 2048,  lB + 4096);
    __syncthreads();
    bf16x8 a[4], b[4];
#pragma unroll
    for (int m = 0; m < 4; ++m)
      a[m] = *(const bf16x8*)((const char*)As + (wr + m * 16 + fr) * 64 + kb * 16);
#pragma unroll
    for (int n = 0; n < 4; ++n)
      b[n] = *(const bf16x8*)((const char*)Bs + (wc + n * 16 + fr) * 64 + kb * 16);
#pragma unroll
    for (int m = 0; m < 4; ++m)
#pragma unroll
      for (int n = 0; n < 4; ++n)
        acc[m][n] = MFMA16(a[m], b[n], acc[m][n]);
    __syncthreads();
  }

  float bv[4];
#pragma unroll
  for (int n = 0; n < 4; ++n) bv[n] = bias[col0 + wc + n * 16 + fr];

#pragma unroll
  for (int h = 0; h < 2; ++h) {
    if ((wid >> 1) == h) {
#pragma unroll
      for (int m = 0; m < 4; ++m)
#pragma unroll
        for (int n = 0; n < 4; ++n)
#pragma unroll
          for (int r = 0; r < 4; ++r)
            eps[m * 16 + kb * 4 + r][wc + n * 16 + fr] = (__bf16)(acc[m][n][r] + bv[n]);
    }
    __syncthreads();
    {
      const int row = tid >> 2, ch = tid & 3;
      const uint4* s = (const uint4*)&eps[row][ch * 32];
      uint4* d = (uint4*)(XW + (size_t)(row0 + h * 64 + row) * G_ + col0 + ch * 32);
#pragma unroll
      for (int i = 0; i < 4; ++i) d[i] = s[i];
    }
    __syncthreads();
  }
}

// ----------------------------------------------------- persistent LSTM scan
// 256 blocks (1/CU), 512 threads. Block = 32 batch rows x 32 h-cols, all 4
// gates (wave wg = wid&3 -> gate, mh = wid>>2 -> row half). h double-buffered
// in global; c-state in registers; device-scope barrier between steps.
__global__ __launch_bounds__(512, 1) void lstm_scan(
    const __bf16* __restrict__ WhT, const __bf16* __restrict__ XW,
    __bf16* __restrict__ hb0, __bf16* __restrict__ hb1,
    float* __restrict__ outp, float* __restrict__ hfin,
    float* __restrict__ cfin, unsigned* __restrict__ bar) {
  __shared__ __bf16 As[32 * 1024];     // 64 KB, XOR-swizzled 16B chunks
  __shared__ float  zs[4][32][33];     // gate exchange, padded
  const int tid = threadIdx.x;
  const int lane = tid & 63;
  const int wid = tid >> 6;
  const int bid = blockIdx.x;
  const int bg = (bid >> 3) & 7;
  const int cg = (bid & 7) + (bid >> 6) * 8;   // XCD-affine col groups
  const int b0 = bg * 32;
  const int c0 = cg * 32;

  const int wg = wid & 3;      // gate (i,f,g,o)
  const int mh = wid >> 2;     // row half
  const int fr = lane & 15, kb = lane >> 4;
  const int arow = mh * 16 + fr;
  const __bf16* wb0 = WhT + (size_t)(wg * 1024 + c0 + fr) * H_;
  const __bf16* wb1 = WhT + (size_t)(wg * 1024 + c0 + 16 + fr) * H_;

  const int crow = tid >> 4, ccolb = (tid & 15) * 2;
  const size_t sidx = (size_t)(b0 + crow) * H_ + c0 + ccolb;
  float creg0 = 0.f, creg1 = 0.f;

  const int chunk = tid & 127, rsub = tid >> 7;

#pragma unroll 1
  for (int t = 0; t < S_; ++t) {
    const __bf16* hin = (t & 1) ? hb1 : hb0;
    __bf16* hout = (t & 1) ? hb0 : hb1;

    // T14: prefetch cell inputs (4 gates x 2 bf16) before the MFMA phase.
    const size_t xwbase = ((size_t)(b0 + crow) * S_ + t) * G_ + c0 + ccolb;
    const unsigned xw0 = *(const unsigned*)(XW + xwbase);
    const unsigned xw1 = *(const unsigned*)(XW + xwbase + 1024);
    const unsigned xw2 = *(const unsigned*)(XW + xwbase + 2048);
    const unsigned xw3 = *(const unsigned*)(XW + xwbase + 3072);

    // Stage h rows [b0,b0+32) -> As (linear LDS dest, source XOR-swizzled).
#pragma unroll
    for (int cc = 0; cc < 8; ++cc) {
      const int row = cc * 4 + rsub;
      const char* src = (const char*)(hin + (size_t)(b0 + row) * H_) +
                        ((chunk ^ (row & 7)) * 16);
      gload_lds16(src, (char*)As + cc * 8192 + wid * 1024);
    }
    __syncthreads();

    f32x4 acc0 = {0.f, 0.f, 0.f, 0.f}, acc1 = {0.f, 0.f, 0.f, 0.f};
#pragma unroll 4
    for (int kt = 0; kt < 32; ++kt) {
      const int ck = kt * 4 + kb;
      bf16x8 a = *(const bf16x8*)((const char*)As + arow * 2048 +
                                  ((ck ^ (arow & 7)) * 16));
      bf16x8 bv0 = *(const bf16x8*)(wb0 + kt * 32 + kb * 8);
      bf16x8 bv1 = *(const bf16x8*)(wb1 + kt * 32 + kb * 8);
      acc0 = MFMA16(a, bv0, acc0);
      acc1 = MFMA16(a, bv1, acc1);
    }
#pragma unroll
    for (int r = 0; r < 4; ++r) {
      zs[wg][mh * 16 + kb * 4 + r][fr]      = acc0[r];
      zs[wg][mh * 16 + kb * 4 + r][16 + fr] = acc1[r];
    }
    __syncthreads();

    // Cell (fp32), c in registers.
    const float zi0 = zs[0][crow][ccolb]     + bf_lo(xw0);
    const float zf0 = zs[1][crow][ccolb]     + bf_lo(xw1);
    const float zg0 = zs[2][crow][ccolb]     + bf_lo(xw2);
    const float zo0 = zs[3][crow][ccolb]     + bf_lo(xw3);
    const float zi1 = zs[0][crow][ccolb + 1] + bf_hi(xw0);
    const float zf1 = zs[1][crow][ccolb + 1] + bf_hi(xw1);
    const float zg1 = zs[2][crow][ccolb + 1] + bf_hi(xw2);
    const float zo1 = zs[3][crow][ccolb + 1] + bf_hi(xw3);
    const float cv0 = sigm(zf0) * creg0 + sigm(zi0) * tanhfast(zg0);
    const float cv1 = sigm(zf1) * creg1 + sigm(zi1) * tanhfast(zg1);
    creg0 = cv0; creg1 = cv1;
    const float hv0 = sigm(zo0) * tanhfast(cv0);
    const float hv1 = sigm(zo1) * tanhfast(cv1);

    float2 o2; o2.x = hv0; o2.y = hv1;
    *(float2*)(outp + ((size_t)(b0 + crow) * S_ + t) * H_ + c0 + ccolb) = o2;
    bf16x2 hp; hp[0] = (__bf16)hv0; hp[1] = (__bf16)hv1;
    *(bf16x2*)(hout + sidx) = hp;
    if (t == S_ - 1) {
      float2 c2; c2.x = cv0; c2.y = cv1;
      *(float2*)(hfin + sidx) = o2;
      *(float2*)(cfin + sidx) = c2;
    }

    if (t < S_ - 1) {
      __syncthreads();               // drain every wave's h stores to L2
      if (tid == 0) {
        __hip_atomic_fetch_add(bar, 1u, __ATOMIC_RELEASE, __HIP_MEMORY_SCOPE_AGENT);
        const unsigned target = (unsigned)(t + 1) * 256u;
        while (__hip_atomic_load(bar, __ATOMIC_RELAXED, __HIP_MEMORY_SCOPE_AGENT) < target)
          __builtin_amdgcn_s_sleep(2);
        (void)__hip_atomic_load(bar, __ATOMIC_ACQUIRE, __HIP_MEMORY_SCOPE_AGENT);
      }
      __syncthreads();
    }
  }
}

// ----------------------------------------------------------------- launcher
extern "C" void kernel_launch(void* const* d_in, const int* in_sizes, int n_in,
                              void* d_out, int out_size, void* d_ws, size_t ws_size,
                              hipStream_t stream) {
  const int*   inp  = (const int*)d_in[0];
  const float* emb  = (const float*)d_in[1];
  const float* Wi   = (const float*)d_in[2];
  const float* Wh   = (const float*)d_in[3];
  const float* bias = (const float*)d_in[4];

  char* ws = (char*)d_ws;
  __bf16* WiT = (__bf16*)(ws);
  __bf16* WhT = (__bf16*)(ws + 8388608);
  __bf16* hb0 = (__bf16*)(ws + 16777216);
  __bf16* hb1 = (__bf16*)(ws + 17301504);
  __bf16* X   = (__bf16*)(ws + 17825792);
  __bf16* XW  = (__bf16*)(ws + 152043520);

  float* outp = (float*)d_out;
  float* hfin = outp + (size_t)M_ * H_;
  float* cfin = hfin + (size_t)B_ * H_;
  unsigned* bar = (unsigned*)hfin;   // overwritten only at t=S-1 (after last use)

  zero_init<<<128, 256, 0, stream>>>((uint4*)hb0, bar);
  transpose_cast<<<dim3(128, 32), 256, 0, stream>>>(Wi, WiT);
  transpose_cast<<<dim3(128, 32), 256, 0, stream>>>(Wh, WhT);
  gather_cast<<<32768, 256, 0, stream>>>(inp, emb, X);
  gemm_xw<<<16384, 256, 0, stream>>>(X, WiT, bias, XW);
  lstm_scan<<<256, 512, 0, stream>>>(WhT, XW, hb0, hb1, outp, hfin, cfin, bar);
}

// Round 3
// 6260.201 us; speedup vs baseline: 1.4169x; 1.4169x over previous
//
#include <hip/hip_runtime.h>
#include <hip/hip_bf16.h>
#include <stdint.h>

// EncoderFLAX: x = emb[inputs]; xW = x@Wi + b; LSTM scan over S with Wh.
// B=256 S=256 V=32000 E=1024 H=1024. Outputs: [B,S,H] fp32, h [B,H], c [B,H].
//
// Round 3 changes (vs round 2):
//  - barrier: flags-array (store+poll) instead of single-counter fetch_add
//    (round 2: 256 serialized agent RMWs/step ~= 26us/step stall).
//  - h exchange: write-through sc0sc1 stores + bypass sc0sc1 staging loads
//    (reg-staged, swizzled ds_write) -> no wbL2/inv per step, Wh stays in L2.
//  - Wh inner loop: register double-buffer (groups of 8 kt), static indexing.
//  - flags live in the dead X region (zeroed after gemm_xw), NOT in hfin.
//
// ws layout (bytes):
//   WiT 0..8388608, WhT ..16777216, hb0 ..17301504, hb1 ..17825792,
//   X ..152043520 (first 1KB reused as barrier flags during the scan),
//   XW ..688914432

#define B_ 256
#define S_ 256
#define E_ 1024
#define H_ 1024
#define G_ 4096
#define M_ 65536

typedef float  f32x4  __attribute__((ext_vector_type(4)));
typedef __bf16 bf16x8 __attribute__((ext_vector_type(8)));

#define MFMA16(a, b, c) __builtin_amdgcn_mfma_f32_16x16x32_bf16((a), (b), (c), 0, 0, 0)

__device__ __forceinline__ void gload_lds16(const void* g, void* l) {
  __builtin_amdgcn_global_load_lds(
      (__attribute__((address_space(1))) void*)(g),
      (__attribute__((address_space(3))) void*)(l), 16, 0, 0);
}

__device__ __forceinline__ float sigm(float x) { return 1.f / (1.f + __expf(-x)); }
__device__ __forceinline__ float tanhfast(float x) {
  float e = __expf(-2.f * x);
  return (1.f - e) / (1.f + e);
}
__device__ __forceinline__ float bf_lo(unsigned v) { return __uint_as_float(v << 16); }
__device__ __forceinline__ float bf_hi(unsigned v) { return __uint_as_float(v & 0xffff0000u); }

// ---------------------------------------------------------------- zero init
__global__ __launch_bounds__(256) void zero_init(uint4* h16) {
  int i = blockIdx.x * 256 + threadIdx.x;
  uint4 z; z.x = z.y = z.z = z.w = 0u;
  if (i < 32768) h16[i] = z;            // hb0: 262144 bf16 = 32768 x 16B
}
__global__ __launch_bounds__(256) void zero_flags(unsigned* flags) {
  flags[threadIdx.x] = 0u;
}

// ------------------------------------------------- transpose+cast [1024][4096]
__global__ __launch_bounds__(256) void transpose_cast(const float* __restrict__ in,
                                                      __bf16* __restrict__ out) {
  __shared__ __bf16 tile[32][33];
  const int c0 = blockIdx.x * 32;
  const int r0 = blockIdx.y * 32;
  const int tx = threadIdx.x & 31, ty = threadIdx.x >> 5;
#pragma unroll
  for (int p = 0; p < 4; ++p) {
    const int rr = ty + p * 8;
    tile[rr][tx] = (__bf16)in[(size_t)(r0 + rr) * G_ + c0 + tx];
  }
  __syncthreads();
#pragma unroll
  for (int p = 0; p < 4; ++p) {
    const int rr = ty + p * 8;
    out[(size_t)(c0 + rr) * E_ + r0 + tx] = tile[tx][rr];
  }
}

// ------------------------------------------------------- embedding gather+cast
union U16b { uint4 v; __bf16 h[8]; };
__global__ __launch_bounds__(256) void gather_cast(const int* __restrict__ idx,
                                                   const float* __restrict__ emb,
                                                   __bf16* __restrict__ X) {
  const size_t gid  = (size_t)blockIdx.x * 256 + threadIdx.x;
  const size_t base = gid * 8;
  const int r = (int)(base >> 10);
  const int e = (int)(base & 1023);
  const int row = idx[r];
  const float4* s = (const float4*)(emb + (size_t)row * E_ + e);
  const float4 v0 = s[0], v1 = s[1];
  U16b u;
  u.h[0] = (__bf16)v0.x; u.h[1] = (__bf16)v0.y; u.h[2] = (__bf16)v0.z; u.h[3] = (__bf16)v0.w;
  u.h[4] = (__bf16)v1.x; u.h[5] = (__bf16)v1.y; u.h[6] = (__bf16)v1.z; u.h[7] = (__bf16)v1.w;
  *(uint4*)(X + base) = u.v;
}

// --------------------------------------------------- xW GEMM (m97 structure)
__global__ __launch_bounds__(256) void gemm_xw(const __bf16* __restrict__ X,
                                               const __bf16* __restrict__ WiT,
                                               const float* __restrict__ bias,
                                               __bf16* __restrict__ XW) {
  __shared__ __bf16 As[128 * 32];
  __shared__ __bf16 Bs[128 * 32];
  __shared__ __bf16 eps[64][136];
  const int tid = threadIdx.x;
  const int lane = tid & 63;
  const int wid = tid >> 6;
  const int bn = blockIdx.x & 31;
  const int bm = blockIdx.x >> 5;
  const int row0 = bm * 128, col0 = bn * 128;
  const int wr = (wid >> 1) * 64, wc = (wid & 1) * 64;
  const int srow = tid >> 2, schunk = tid & 3;
  const char* gA = (const char*)(X + (size_t)(row0 + srow) * E_) + schunk * 16;
  const char* gB = (const char*)(WiT + (size_t)(col0 + srow) * E_) + schunk * 16;
  char* lA = (char*)As + wid * 1024;
  char* lB = (char*)Bs + wid * 1024;
  const int fr = lane & 15, kb = lane >> 4;

  f32x4 acc[4][4] = {};

  for (int kt = 0; kt < 32; ++kt) {
    gload_lds16(gA + kt * 64,              lA);
    gload_lds16(gA + kt * 64 + 64 * 2048,  lA + 4096);
    gload_lds16(gB + kt * 64,              lB);
    gload_lds16(gB + kt * 64 + 64 * 2048,  lB + 4096);
    __syncthreads();
    bf16x8 a[4], b[4];
#pragma unroll
    for (int m = 0; m < 4; ++m)
      a[m] = *(const bf16x8*)((const char*)As + (wr + m * 16 + fr) * 64 + kb * 16);
#pragma unroll
    for (int n = 0; n < 4; ++n)
      b[n] = *(const bf16x8*)((const char*)Bs + (wc + n * 16 + fr) * 64 + kb * 16);
#pragma unroll
    for (int m = 0; m < 4; ++m)
#pragma unroll
      for (int n = 0; n < 4; ++n)
        acc[m][n] = MFMA16(a[m], b[n], acc[m][n]);
    __syncthreads();
  }

  float bv[4];
#pragma unroll
  for (int n = 0; n < 4; ++n) bv[n] = bias[col0 + wc + n * 16 + fr];

#pragma unroll
  for (int h = 0; h < 2; ++h) {
    if ((wid >> 1) == h) {
#pragma unroll
      for (int m = 0; m < 4; ++m)
#pragma unroll
        for (int n = 0; n < 4; ++n)
#pragma unroll
          for (int r = 0; r < 4; ++r)
            eps[m * 16 + kb * 4 + r][wc + n * 16 + fr] = (__bf16)(acc[m][n][r] + bv[n]);
    }
    __syncthreads();
    {
      const int row = tid >> 2, ch = tid & 3;
      const uint4* s = (const uint4*)&eps[row][ch * 32];
      uint4* d = (uint4*)(XW + (size_t)(row0 + h * 64 + row) * G_ + col0 + ch * 32);
#pragma unroll
      for (int i = 0; i < 4; ++i) d[i] = s[i];
    }
    __syncthreads();
  }
}

// --------------------------------------------------- scan helpers (static idx)
__device__ __forceinline__ void load_grp(const __bf16* wb0, const __bf16* wb1,
                                         int gbase, int kb,
                                         bf16x8 (&B0)[8], bf16x8 (&B1)[8]) {
#pragma unroll
  for (int j = 0; j < 8; ++j) {
    B0[j] = *(const bf16x8*)(wb0 + (gbase + j) * 32 + kb * 8);
    B1[j] = *(const bf16x8*)(wb1 + (gbase + j) * 32 + kb * 8);
  }
}
__device__ __forceinline__ void mfma_grp(const char* Asb, int arow, int kb, int gbase,
                                         bf16x8 (&B0)[8], bf16x8 (&B1)[8],
                                         f32x4& a0, f32x4& a1) {
#pragma unroll
  for (int j = 0; j < 8; ++j) {
    const int ck = (gbase + j) * 4 + kb;
    bf16x8 a = *(const bf16x8*)(Asb + arow * 2048 + ((ck ^ (arow & 7)) * 16));
    a0 = MFMA16(a, B0[j], a0);
    a1 = MFMA16(a, B1[j], a1);
  }
}

// ----------------------------------------------------- persistent LSTM scan
// 256 blocks (1/CU), 512 threads. Block = 32 batch rows x 32 h-cols.
// Inter-step sync: per-block flag store + per-thread poll (no atomic RMW).
__global__ __launch_bounds__(512, 2) void lstm_scan(
    const __bf16* __restrict__ WhT, const __bf16* __restrict__ XW,
    __bf16* __restrict__ hb0, __bf16* __restrict__ hb1,
    float* __restrict__ outp, float* __restrict__ hfin,
    float* __restrict__ cfin, unsigned* __restrict__ flags) {
  __shared__ __bf16 As[32 * 1024];     // 64 KB, XOR-swizzled 16B chunks
  __shared__ float  zs[4][32][34];     // gate exchange, even stride for b64
  const int tid = threadIdx.x;
  const int lane = tid & 63;
  const int wid = tid >> 6;
  const int bid = blockIdx.x;
  const int bg = (bid >> 3) & 7;
  const int cg = (bid & 7) + (bid >> 6) * 8;   // XCD-affine col groups
  const int b0 = bg * 32;
  const int c0 = cg * 32;

  const int wg = wid & 3;      // gate (i,f,g,o)
  const int mh = wid >> 2;     // row half
  const int fr = lane & 15, kb = lane >> 4;
  const int arow = mh * 16 + fr;
  const __bf16* wb0 = WhT + (size_t)(wg * 1024 + c0 + fr) * H_;
  const __bf16* wb1 = WhT + (size_t)(wg * 1024 + c0 + 16 + fr) * H_;

  const int crow = tid >> 4, ccolb = (tid & 15) * 2;
  const size_t sidx = (size_t)(b0 + crow) * H_ + c0 + ccolb;
  float creg0 = 0.f, creg1 = 0.f;

#pragma unroll 1
  for (int t = 0; t < S_; ++t) {
    const __bf16* hin = (t & 1) ? hb1 : hb0;
    __bf16* hout = (t & 1) ? hb0 : hb1;

    // Prefetch cell inputs (4 gates x 2 bf16) before the MFMA phase.
    const size_t xwbase = ((size_t)(b0 + crow) * S_ + t) * G_ + c0 + ccolb;
    const unsigned xw0 = *(const unsigned*)(XW + xwbase);
    const unsigned xw1 = *(const unsigned*)(XW + xwbase + 1024);
    const unsigned xw2 = *(const unsigned*)(XW + xwbase + 2048);
    const unsigned xw3 = *(const unsigned*)(XW + xwbase + 3072);

    // Stage h rows [b0,b0+32): bypass loads (sc0 sc1, fresh from MALL) ->
    // regs -> XOR-swizzled ds_write_b128. ci = i*512+tid: 1KB/wave contiguous.
    {
      uint4 sv[8];
#pragma unroll
      for (int i = 0; i < 8; ++i) {
        const int ci = i * 512 + tid;
        const int row = ci >> 7, cch = ci & 127;
        const void* src = (const char*)(hin + (size_t)(b0 + row) * H_) + cch * 16;
        asm volatile("global_load_dwordx4 %0, %1, off sc0 sc1"
                     : "=v"(sv[i]) : "v"(src) : "memory");
      }
      asm volatile("s_waitcnt vmcnt(0)" ::: "memory");
      __builtin_amdgcn_sched_barrier(0);
#pragma unroll
      for (int i = 0; i < 8; ++i) {
        const int ci = i * 512 + tid;
        const int row = ci >> 7, cch = ci & 127;
        *(uint4*)((char*)As + row * 2048 + ((cch ^ (row & 7)) * 16)) = sv[i];
      }
    }
    __syncthreads();

    // MFMA phase: Wh register double-buffer, groups of 8 kt.
    f32x4 acc0 = {0.f, 0.f, 0.f, 0.f}, acc1 = {0.f, 0.f, 0.f, 0.f};
    {
      bf16x8 pb0[8], pb1[8], qb0[8], qb1[8];
      load_grp(wb0, wb1, 0, kb, pb0, pb1);
      load_grp(wb0, wb1, 8, kb, qb0, qb1);
      mfma_grp((const char*)As, arow, kb, 0, pb0, pb1, acc0, acc1);
      load_grp(wb0, wb1, 16, kb, pb0, pb1);
      mfma_grp((const char*)As, arow, kb, 8, qb0, qb1, acc0, acc1);
      load_grp(wb0, wb1, 24, kb, qb0, qb1);
      mfma_grp((const char*)As, arow, kb, 16, pb0, pb1, acc0, acc1);
      mfma_grp((const char*)As, arow, kb, 24, qb0, qb1, acc0, acc1);
    }
#pragma unroll
    for (int r = 0; r < 4; ++r) {
      zs[wg][mh * 16 + kb * 4 + r][fr]      = acc0[r];
      zs[wg][mh * 16 + kb * 4 + r][16 + fr] = acc1[r];
    }
    __syncthreads();

    // Cell (fp32), c in registers.
    const float2 zi2 = *(const float2*)&zs[0][crow][ccolb];
    const float2 zf2 = *(const float2*)&zs[1][crow][ccolb];
    const float2 zg2 = *(const float2*)&zs[2][crow][ccolb];
    const float2 zo2 = *(const float2*)&zs[3][crow][ccolb];
    const float zi0 = zi2.x + bf_lo(xw0), zi1 = zi2.y + bf_hi(xw0);
    const float zf0 = zf2.x + bf_lo(xw1), zf1 = zf2.y + bf_hi(xw1);
    const float zg0 = zg2.x + bf_lo(xw2), zg1 = zg2.y + bf_hi(xw2);
    const float zo0 = zo2.x + bf_lo(xw3), zo1 = zo2.y + bf_hi(xw3);
    const float cv0 = sigm(zf0) * creg0 + sigm(zi0) * tanhfast(zg0);
    const float cv1 = sigm(zf1) * creg1 + sigm(zi1) * tanhfast(zg1);
    creg0 = cv0; creg1 = cv1;
    const float hv0 = sigm(zo0) * tanhfast(cv0);
    const float hv1 = sigm(zo1) * tanhfast(cv1);

    float2 o2; o2.x = hv0; o2.y = hv1;
    *(float2*)(outp + ((size_t)(b0 + crow) * S_ + t) * H_ + c0 + ccolb) = o2;

    union { __bf16 h[2]; unsigned u; } up;
    up.h[0] = (__bf16)hv0; up.h[1] = (__bf16)hv1;
    {
      void* dst = (void*)(hout + sidx);
      asm volatile("global_store_dword %0, %1, off sc0 sc1"
                   :: "v"(dst), "v"(up.u) : "memory");
    }
    if (t == S_ - 1) {
      float2 c2; c2.x = cv0; c2.y = cv1;
      *(float2*)(hfin + sidx) = o2;
      *(float2*)(cfin + sidx) = c2;
    }

    if (t < S_ - 1) {
      __syncthreads();   // all waves' sc0sc1 h-stores drained (vmcnt0 @ barrier)
      if (tid == 0)
        __hip_atomic_store(&flags[bid], (unsigned)(t + 1),
                           __ATOMIC_RELAXED, __HIP_MEMORY_SCOPE_AGENT);
      if (tid < 256) {
        const unsigned tgt = (unsigned)(t + 1);
        while (__hip_atomic_load(&flags[tid], __ATOMIC_RELAXED,
                                 __HIP_MEMORY_SCOPE_AGENT) < tgt)
          __builtin_amdgcn_s_sleep(1);
      }
      __syncthreads();
    }
  }
}

// ----------------------------------------------------------------- launcher
extern "C" void kernel_launch(void* const* d_in, const int* in_sizes, int n_in,
                              void* d_out, int out_size, void* d_ws, size_t ws_size,
                              hipStream_t stream) {
  const int*   inp  = (const int*)d_in[0];
  const float* emb  = (const float*)d_in[1];
  const float* Wi   = (const float*)d_in[2];
  const float* Wh   = (const float*)d_in[3];
  const float* bias = (const float*)d_in[4];

  char* ws = (char*)d_ws;
  __bf16* WiT = (__bf16*)(ws);
  __bf16* WhT = (__bf16*)(ws + 8388608);
  __bf16* hb0 = (__bf16*)(ws + 16777216);
  __bf16* hb1 = (__bf16*)(ws + 17301504);
  __bf16* X   = (__bf16*)(ws + 17825792);
  __bf16* XW  = (__bf16*)(ws + 152043520);
  unsigned* flags = (unsigned*)(ws + 17825792);  // overlays dead X during scan

  float* outp = (float*)d_out;
  float* hfin = outp + (size_t)M_ * H_;
  float* cfin = hfin + (size_t)B_ * H_;

  zero_init<<<128, 256, 0, stream>>>((uint4*)hb0);
  transpose_cast<<<dim3(128, 32), 256, 0, stream>>>(Wi, WiT);
  transpose_cast<<<dim3(128, 32), 256, 0, stream>>>(Wh, WhT);
  gather_cast<<<32768, 256, 0, stream>>>(inp, emb, X);
  gemm_xw<<<16384, 256, 0, stream>>>(X, WiT, bias, XW);
  zero_flags<<<1, 256, 0, stream>>>(flags);   // X is dead from here on
  lstm_scan<<<256, 512, 0, stream>>>(WhT, XW, hb0, hb1, outp, hfin, cfin, flags);
}

// Round 6
// 4095.290 us; speedup vs baseline: 2.1659x; 1.5286x over previous
//
#include <hip/hip_runtime.h>
#include <hip/hip_bf16.h>
#include <stdint.h>

// EncoderFLAX: x = emb[inputs]; xW = x@Wi + b; LSTM scan over S with Wh.
// B=256 S=256 V=32000 E=1024 H=1024. Outputs: [B,S,H] fp32, h [B,H], c [B,H].
//
// Round 6 (bisection): round 4/5's compute improvements + round 3's PROVEN
// sync, to isolate the round-4/5 failure.
//  kept from r4/5 (math-verified):
//   - (gate, col-half) wave remap; each wave does both row halves -> Wh L2
//     reads deduped (256KB/block/step).
//   - XW permuted [row_m][cg(32)][gate(4)][col(32)]: block reads 256B/row
//     contiguous; plain cached loads (round-3 style), issued at loop top.
//  reverted to round 3 (proven):
//   - flag store via __hip_atomic_store(RELAXED, AGENT) by tid 0;
//   - poll via __hip_atomic_load by tid<256 + __syncthreads;
//   - plain outp stores before the vmcnt(0)+s_barrier drain;
//   - no sc0sc1 on flags; no overlapped stores inside the poll window.
//
// ws layout (bytes):
//   WiT 0..8388608, WhT ..16777216, hb0 ..17301504, hb1 ..17825792,
//   X ..152043520 (first 1KB reused as barrier flags during the scan),
//   XW ..688914432

#define B_ 256
#define S_ 256
#define E_ 1024
#define H_ 1024
#define G_ 4096
#define M_ 65536

typedef float  f32x4  __attribute__((ext_vector_type(4)));
typedef __bf16 bf16x8 __attribute__((ext_vector_type(8)));

#define MFMA16(a, b, c) __builtin_amdgcn_mfma_f32_16x16x32_bf16((a), (b), (c), 0, 0, 0)

__device__ __forceinline__ void gload_lds16(const void* g, void* l) {
  __builtin_amdgcn_global_load_lds(
      (__attribute__((address_space(1))) void*)(g),
      (__attribute__((address_space(3))) void*)(l), 16, 0, 0);
}

__device__ __forceinline__ float sigm(float x) { return 1.f / (1.f + __expf(-x)); }
__device__ __forceinline__ float tanhfast(float x) {
  float e = __expf(-2.f * x);
  return (1.f - e) / (1.f + e);
}
__device__ __forceinline__ float bf_lo(unsigned v) { return __uint_as_float(v << 16); }
__device__ __forceinline__ float bf_hi(unsigned v) { return __uint_as_float(v & 0xffff0000u); }

// ---------------------------------------------------------------- zero init
__global__ __launch_bounds__(256) void zero_init(uint4* h16) {
  int i = blockIdx.x * 256 + threadIdx.x;
  uint4 z; z.x = z.y = z.z = z.w = 0u;
  if (i < 32768) h16[i] = z;            // hb0: 262144 bf16 = 32768 x 16B
}
__global__ __launch_bounds__(256) void zero_flags(unsigned* flags) {
  flags[threadIdx.x] = 0u;
}

// ------------------------------------------------- transpose+cast [1024][4096]
__global__ __launch_bounds__(256) void transpose_cast(const float* __restrict__ in,
                                                      __bf16* __restrict__ out) {
  __shared__ __bf16 tile[32][33];
  const int c0 = blockIdx.x * 32;
  const int r0 = blockIdx.y * 32;
  const int tx = threadIdx.x & 31, ty = threadIdx.x >> 5;
#pragma unroll
  for (int p = 0; p < 4; ++p) {
    const int rr = ty + p * 8;
    tile[rr][tx] = (__bf16)in[(size_t)(r0 + rr) * G_ + c0 + tx];
  }
  __syncthreads();
#pragma unroll
  for (int p = 0; p < 4; ++p) {
    const int rr = ty + p * 8;
    out[(size_t)(c0 + rr) * E_ + r0 + tx] = tile[tx][rr];
  }
}

// ------------------------------------------------------- embedding gather+cast
union U16b { uint4 v; __bf16 h[8]; };
__global__ __launch_bounds__(256) void gather_cast(const int* __restrict__ idx,
                                                   const float* __restrict__ emb,
                                                   __bf16* __restrict__ X) {
  const size_t gid  = (size_t)blockIdx.x * 256 + threadIdx.x;
  const size_t base = gid * 8;
  const int r = (int)(base >> 10);
  const int e = (int)(base & 1023);
  const int row = idx[r];
  const float4* s = (const float4*)(emb + (size_t)row * E_ + e);
  const float4 v0 = s[0], v1 = s[1];
  U16b u;
  u.h[0] = (__bf16)v0.x; u.h[1] = (__bf16)v0.y; u.h[2] = (__bf16)v0.z; u.h[3] = (__bf16)v0.w;
  u.h[4] = (__bf16)v1.x; u.h[5] = (__bf16)v1.y; u.h[6] = (__bf16)v1.z; u.h[7] = (__bf16)v1.w;
  *(uint4*)(X + base) = u.v;
}

// --------------------------------------------------- xW GEMM (m97 structure)
// Writes XW PERMUTED: elem offset = ((row*32 + cg)*4 + gate)*32 + col_in_cg.
__global__ __launch_bounds__(256) void gemm_xw(const __bf16* __restrict__ X,
                                               const __bf16* __restrict__ WiT,
                                               const float* __restrict__ bias,
                                               __bf16* __restrict__ XW2) {
  __shared__ __bf16 As[128 * 32];
  __shared__ __bf16 Bs[128 * 32];
  __shared__ __bf16 eps[64][136];
  const int tid = threadIdx.x;
  const int lane = tid & 63;
  const int wid = tid >> 6;
  const int bn = blockIdx.x & 31;
  const int bm = blockIdx.x >> 5;
  const int row0 = bm * 128, col0 = bn * 128;
  const int wr = (wid >> 1) * 64, wc = (wid & 1) * 64;
  const int srow = tid >> 2, schunk = tid & 3;
  const char* gA = (const char*)(X + (size_t)(row0 + srow) * E_) + schunk * 16;
  const char* gB = (const char*)(WiT + (size_t)(col0 + srow) * E_) + schunk * 16;
  char* lA = (char*)As + wid * 1024;
  char* lB = (char*)Bs + wid * 1024;
  const int fr = lane & 15, kb = lane >> 4;

  f32x4 acc[4][4] = {};

  for (int kt = 0; kt < 32; ++kt) {
    gload_lds16(gA + kt * 64,              lA);
    gload_lds16(gA + kt * 64 + 64 * 2048,  lA + 4096);
    gload_lds16(gB + kt * 64,              lB);
    gload_lds16(gB + kt * 64 + 64 * 2048,  lB + 4096);
    __syncthreads();
    bf16x8 a[4], b[4];
#pragma unroll
    for (int m = 0; m < 4; ++m)
      a[m] = *(const bf16x8*)((const char*)As + (wr + m * 16 + fr) * 64 + kb * 16);
#pragma unroll
    for (int n = 0; n < 4; ++n)
      b[n] = *(const bf16x8*)((const char*)Bs + (wc + n * 16 + fr) * 64 + kb * 16);
#pragma unroll
    for (int m = 0; m < 4; ++m)
#pragma unroll
      for (int n = 0; n < 4; ++n)
        acc[m][n] = MFMA16(a[m], b[n], acc[m][n]);
    __syncthreads();
  }

  float bv[4];
#pragma unroll
  for (int n = 0; n < 4; ++n) bv[n] = bias[col0 + wc + n * 16 + fr];

  const int gate = col0 >> 10;             // 128-col tile spans one gate
  const int cg0  = (col0 & 1023) >> 5;     // first of 4 col-groups

#pragma unroll
  for (int h = 0; h < 2; ++h) {
    if ((wid >> 1) == h) {
#pragma unroll
      for (int m = 0; m < 4; ++m)
#pragma unroll
        for (int n = 0; n < 4; ++n)
#pragma unroll
          for (int r = 0; r < 4; ++r)
            eps[m * 16 + kb * 4 + r][wc + n * 16 + fr] = (__bf16)(acc[m][n][r] + bv[n]);
    }
    __syncthreads();
    {
      const int row = tid >> 2, ch = tid & 3;
      const int r_m = row0 + h * 64 + row;
      const uint4* s = (const uint4*)&eps[row][ch * 32];
      uint4* d = (uint4*)(XW2 + ((size_t)r_m * 32 + (cg0 + ch)) * 128 + gate * 32);
#pragma unroll
      for (int i = 0; i < 4; ++i) d[i] = s[i];
    }
    __syncthreads();
  }
}

// --------------------------------------------------- scan helpers (static idx)
__device__ __forceinline__ void load8(const __bf16* wb, int gbase, bf16x8 (&P)[8]) {
#pragma unroll
  for (int j = 0; j < 8; ++j)
    P[j] = *(const bf16x8*)(wb + (gbase + j) * 32);
}
__device__ __forceinline__ void mfma8(const char* Asb, int fr, int kb, int gbase,
                                      bf16x8 (&P)[8], f32x4& a0, f32x4& a1) {
#pragma unroll
  for (int j = 0; j < 8; ++j) {
    const int ck = (gbase + j) * 4 + kb;
    bf16x8 alo = *(const bf16x8*)(Asb + fr * 2048 + ((ck ^ (fr & 7)) * 16));
    bf16x8 ahi = *(const bf16x8*)(Asb + (16 + fr) * 2048 + ((ck ^ (fr & 7)) * 16));
    a0 = MFMA16(alo, P[j], a0);
    a1 = MFMA16(ahi, P[j], a1);
  }
}

// ----------------------------------------------------- persistent LSTM scan
// 256 blocks (1/CU), 512 threads. Block = 32 batch rows x 32 h-cols.
// Wave = (gate, col-half); both row-halves per wave (Wh reads deduped).
// Sync = round-3 proven: atomic flag store by tid0 + atomic poll by tid<256.
__global__ __launch_bounds__(512, 1) void lstm_scan(
    const __bf16* __restrict__ WhT, const __bf16* __restrict__ XW2,
    __bf16* __restrict__ hb0, __bf16* __restrict__ hb1,
    float* __restrict__ outp, float* __restrict__ hfin,
    float* __restrict__ cfin, unsigned* __restrict__ flags) {
  __shared__ __bf16 As[32 * 1024];     // 64 KB, XOR-swizzled 16B chunks
  __shared__ float  zs[4][32][34];
  const int tid = threadIdx.x;
  const int lane = tid & 63;
  const int wid = tid >> 6;
  const int bid = blockIdx.x;
  const int bg = (bid >> 3) & 7;
  const int cg = (bid & 7) + (bid >> 6) * 8;   // XCD-affine col groups
  const int b0 = bg * 32;
  const int c0 = cg * 32;

  const int wg = wid & 3;      // gate (i,f,g,o)
  const int nh = wid >> 2;     // col half
  const int fr = lane & 15, kb = lane >> 4;
  const __bf16* wb = WhT + (size_t)(wg * 1024 + c0 + nh * 16 + fr) * H_ + kb * 8;

  const int crow = tid >> 4, ccolb = (tid & 15) * 2;
  const size_t sidx = (size_t)(b0 + crow) * H_ + c0 + ccolb;
  const __bf16* xwrow = XW2 + ((size_t)(b0 + crow) * S_ * 32 + cg) * 128 + ccolb;
  float creg0 = 0.f, creg1 = 0.f;

#pragma unroll 1
  for (int t = 0; t < S_; ++t) {
    const __bf16* hin = (t & 1) ? hb1 : hb0;
    __bf16* hout = (t & 1) ? hb0 : hb1;

    // XW cell inputs for step t: plain cached loads (gemm-written, static
    // data -> no sync needed); issued at loop top so latency overlaps.
    const __bf16* p = xwrow + (size_t)t * 4096;
    const unsigned xw0 = *(const unsigned*)(p);
    const unsigned xw1 = *(const unsigned*)(p + 32);
    const unsigned xw2 = *(const unsigned*)(p + 64);
    const unsigned xw3 = *(const unsigned*)(p + 96);

    // ---- wait for h(t-1) visibility (round-3 proven poll) ----
    if (t > 0) {
      if (tid < 256) {
        const unsigned tgt = (unsigned)t;
        while (__hip_atomic_load(&flags[tid], __ATOMIC_RELAXED,
                                 __HIP_MEMORY_SCOPE_AGENT) < tgt)
          __builtin_amdgcn_s_sleep(1);
      }
      __syncthreads();
    }

    // ---- stage h rows [b0,b0+32): bypass loads -> swizzled ds_write ----
    {
      uint4 sv[8];
#pragma unroll
      for (int i = 0; i < 8; ++i) {
        const int ci = i * 512 + tid;
        const int row = ci >> 7, cch = ci & 127;
        const void* src = (const char*)(hin + (size_t)(b0 + row) * H_) + cch * 16;
        asm volatile("global_load_dwordx4 %0, %1, off sc0 sc1"
                     : "=&v"(sv[i]) : "v"(src) : "memory");
      }
      asm volatile("s_waitcnt vmcnt(0)" ::: "memory");
      __builtin_amdgcn_sched_barrier(0);
#pragma unroll
      for (int i = 0; i < 8; ++i) {
        const int ci = i * 512 + tid;
        const int row = ci >> 7, cch = ci & 127;
        *(uint4*)((char*)As + row * 2048 + ((cch ^ (row & 7)) * 16)) = sv[i];
      }
    }
    __syncthreads();

    // ---- MFMA: 32 rows x 16 cols per wave, Wh register double-buffer ----
    f32x4 acc0 = {0.f, 0.f, 0.f, 0.f}, acc1 = {0.f, 0.f, 0.f, 0.f};
    {
      bf16x8 P[8], Q[8];
      load8(wb, 0, P);
      load8(wb, 8, Q);
      mfma8((const char*)As, fr, kb, 0, P, acc0, acc1);
      load8(wb, 16, P);
      mfma8((const char*)As, fr, kb, 8, Q, acc0, acc1);
      load8(wb, 24, Q);
      mfma8((const char*)As, fr, kb, 16, P, acc0, acc1);
      mfma8((const char*)As, fr, kb, 24, Q, acc0, acc1);
    }
#pragma unroll
    for (int r = 0; r < 4; ++r) {
      zs[wg][kb * 4 + r][nh * 16 + fr]      = acc0[r];
      zs[wg][16 + kb * 4 + r][nh * 16 + fr] = acc1[r];
    }
    __syncthreads();

    // ---- cell (fp32), c in registers ----
    const float2 zi2 = *(const float2*)&zs[0][crow][ccolb];
    const float2 zf2 = *(const float2*)&zs[1][crow][ccolb];
    const float2 zg2 = *(const float2*)&zs[2][crow][ccolb];
    const float2 zo2 = *(const float2*)&zs[3][crow][ccolb];
    const float zi0 = zi2.x + bf_lo(xw0), zi1 = zi2.y + bf_hi(xw0);
    const float zf0 = zf2.x + bf_lo(xw1), zf1 = zf2.y + bf_hi(xw1);
    const float zg0 = zg2.x + bf_lo(xw2), zg1 = zg2.y + bf_hi(xw2);
    const float zo0 = zo2.x + bf_lo(xw3), zo1 = zo2.y + bf_hi(xw3);
    const float cv0 = sigm(zf0) * creg0 + sigm(zi0) * tanhfast(zg0);
    const float cv1 = sigm(zf1) * creg1 + sigm(zi1) * tanhfast(zg1);
    creg0 = cv0; creg1 = cv1;
    const float hv0 = sigm(zo0) * tanhfast(cv0);
    const float hv1 = sigm(zo1) * tanhfast(cv1);

    union { __bf16 h[2]; unsigned u; } up;
    up.h[0] = (__bf16)hv0; up.h[1] = (__bf16)hv1;
    float2 o2; o2.x = hv0; o2.y = hv1;

    // outputs: plain store for outp; sc0sc1 write-through for h (round 3)
    *(float2*)(outp + ((size_t)(b0 + crow) * S_ + t) * H_ + c0 + ccolb) = o2;
    {
      void* dst = (void*)(hout + sidx);
      asm volatile("global_store_dword %0, %1, off sc0 sc1"
                   :: "v"(dst), "v"(up.u) : "memory");
    }

    if (t == S_ - 1) {
      float2 c2; c2.x = cv0; c2.y = cv1;
      *(float2*)(hfin + sidx) = o2;
      *(float2*)(cfin + sidx) = c2;
    } else {
      asm volatile("s_waitcnt vmcnt(0)" ::: "memory");   // drain h + outp
      __builtin_amdgcn_s_barrier();
      if (tid == 0)
        __hip_atomic_store(&flags[bid], (unsigned)(t + 1),
                           __ATOMIC_RELAXED, __HIP_MEMORY_SCOPE_AGENT);
    }
  }
}

// ----------------------------------------------------------------- launcher
extern "C" void kernel_launch(void* const* d_in, const int* in_sizes, int n_in,
                              void* d_out, int out_size, void* d_ws, size_t ws_size,
                              hipStream_t stream) {
  const int*   inp  = (const int*)d_in[0];
  const float* emb  = (const float*)d_in[1];
  const float* Wi   = (const float*)d_in[2];
  const float* Wh   = (const float*)d_in[3];
  const float* bias = (const float*)d_in[4];

  char* ws = (char*)d_ws;
  __bf16* WiT = (__bf16*)(ws);
  __bf16* WhT = (__bf16*)(ws + 8388608);
  __bf16* hb0 = (__bf16*)(ws + 16777216);
  __bf16* hb1 = (__bf16*)(ws + 17301504);
  __bf16* X   = (__bf16*)(ws + 17825792);
  __bf16* XW2 = (__bf16*)(ws + 152043520);
  unsigned* flags = (unsigned*)(ws + 17825792);  // overlays dead X during scan

  float* outp = (float*)d_out;
  float* hfin = outp + (size_t)M_ * H_;
  float* cfin = hfin + (size_t)B_ * H_;

  zero_init<<<128, 256, 0, stream>>>((uint4*)hb0);
  transpose_cast<<<dim3(128, 32), 256, 0, stream>>>(Wi, WiT);
  transpose_cast<<<dim3(128, 32), 256, 0, stream>>>(Wh, WhT);
  gather_cast<<<32768, 256, 0, stream>>>(inp, emb, X);
  gemm_xw<<<16384, 256, 0, stream>>>(X, WiT, bias, XW2);
  zero_flags<<<1, 256, 0, stream>>>(flags);   // X is dead from here on
  lstm_scan<<<256, 512, 0, stream>>>(WhT, XW2, hb0, hb1, outp, hfin, cfin, flags);
}

// Round 7
// 3505.243 us; speedup vs baseline: 2.5305x; 1.1683x over previous
//
#include <hip/hip_runtime.h>
#include <hip/hip_bf16.h>
#include <stdint.h>

// EncoderFLAX: x = emb[inputs]; xW = x@Wi + b; LSTM scan over S with Wh.
// B=256 S=256 V=32000 E=1024 H=1024. Outputs: [B,S,H] fp32, h [B,H], c [B,H].
//
// Round 7 = round 6 + bg-local barrier (single change):
//   block (bg,cg) only consumes h rows written by the 32 blocks with the
//   same bg -> sync group = 32 blocks, not 256. flags[bg*64+cg] (256B per
//   group, own cachelines); poll by tid<32 over the group's 32 flags
//   (2 lines/round vs 64). Groups drift independently (disjoint h rows).
// Round 6 proven parts unchanged: atomic flag store/poll, sc0sc1 h
// write-through + bypass staging, (gate,col-half) waves, permuted XW2.
//
// ws layout (bytes):
//   WiT 0..8388608, WhT ..16777216, hb0 ..17301504, hb1 ..17825792,
//   X ..152043520 (first 2KB reused as barrier flags during the scan),
//   XW ..688914432

#define B_ 256
#define S_ 256
#define E_ 1024
#define H_ 1024
#define G_ 4096
#define M_ 65536

typedef float  f32x4  __attribute__((ext_vector_type(4)));
typedef __bf16 bf16x8 __attribute__((ext_vector_type(8)));

#define MFMA16(a, b, c) __builtin_amdgcn_mfma_f32_16x16x32_bf16((a), (b), (c), 0, 0, 0)

__device__ __forceinline__ void gload_lds16(const void* g, void* l) {
  __builtin_amdgcn_global_load_lds(
      (__attribute__((address_space(1))) void*)(g),
      (__attribute__((address_space(3))) void*)(l), 16, 0, 0);
}

__device__ __forceinline__ float sigm(float x) { return 1.f / (1.f + __expf(-x)); }
__device__ __forceinline__ float tanhfast(float x) {
  float e = __expf(-2.f * x);
  return (1.f - e) / (1.f + e);
}
__device__ __forceinline__ float bf_lo(unsigned v) { return __uint_as_float(v << 16); }
__device__ __forceinline__ float bf_hi(unsigned v) { return __uint_as_float(v & 0xffff0000u); }

// ---------------------------------------------------------------- zero init
__global__ __launch_bounds__(256) void zero_init(uint4* h16) {
  int i = blockIdx.x * 256 + threadIdx.x;
  uint4 z; z.x = z.y = z.z = z.w = 0u;
  if (i < 32768) h16[i] = z;            // hb0: 262144 bf16 = 32768 x 16B
}
__global__ __launch_bounds__(256) void zero_flags(unsigned* flags) {
  flags[blockIdx.x * 256 + threadIdx.x] = 0u;   // 512 dwords
}

// ------------------------------------------------- transpose+cast [1024][4096]
__global__ __launch_bounds__(256) void transpose_cast(const float* __restrict__ in,
                                                      __bf16* __restrict__ out) {
  __shared__ __bf16 tile[32][33];
  const int c0 = blockIdx.x * 32;
  const int r0 = blockIdx.y * 32;
  const int tx = threadIdx.x & 31, ty = threadIdx.x >> 5;
#pragma unroll
  for (int p = 0; p < 4; ++p) {
    const int rr = ty + p * 8;
    tile[rr][tx] = (__bf16)in[(size_t)(r0 + rr) * G_ + c0 + tx];
  }
  __syncthreads();
#pragma unroll
  for (int p = 0; p < 4; ++p) {
    const int rr = ty + p * 8;
    out[(size_t)(c0 + rr) * E_ + r0 + tx] = tile[tx][rr];
  }
}

// ------------------------------------------------------- embedding gather+cast
union U16b { uint4 v; __bf16 h[8]; };
__global__ __launch_bounds__(256) void gather_cast(const int* __restrict__ idx,
                                                   const float* __restrict__ emb,
                                                   __bf16* __restrict__ X) {
  const size_t gid  = (size_t)blockIdx.x * 256 + threadIdx.x;
  const size_t base = gid * 8;
  const int r = (int)(base >> 10);
  const int e = (int)(base & 1023);
  const int row = idx[r];
  const float4* s = (const float4*)(emb + (size_t)row * E_ + e);
  const float4 v0 = s[0], v1 = s[1];
  U16b u;
  u.h[0] = (__bf16)v0.x; u.h[1] = (__bf16)v0.y; u.h[2] = (__bf16)v0.z; u.h[3] = (__bf16)v0.w;
  u.h[4] = (__bf16)v1.x; u.h[5] = (__bf16)v1.y; u.h[6] = (__bf16)v1.z; u.h[7] = (__bf16)v1.w;
  *(uint4*)(X + base) = u.v;
}

// --------------------------------------------------- xW GEMM (m97 structure)
// Writes XW PERMUTED: elem offset = ((row*32 + cg)*4 + gate)*32 + col_in_cg.
__global__ __launch_bounds__(256) void gemm_xw(const __bf16* __restrict__ X,
                                               const __bf16* __restrict__ WiT,
                                               const float* __restrict__ bias,
                                               __bf16* __restrict__ XW2) {
  __shared__ __bf16 As[128 * 32];
  __shared__ __bf16 Bs[128 * 32];
  __shared__ __bf16 eps[64][136];
  const int tid = threadIdx.x;
  const int lane = tid & 63;
  const int wid = tid >> 6;
  const int bn = blockIdx.x & 31;
  const int bm = blockIdx.x >> 5;
  const int row0 = bm * 128, col0 = bn * 128;
  const int wr = (wid >> 1) * 64, wc = (wid & 1) * 64;
  const int srow = tid >> 2, schunk = tid & 3;
  const char* gA = (const char*)(X + (size_t)(row0 + srow) * E_) + schunk * 16;
  const char* gB = (const char*)(WiT + (size_t)(col0 + srow) * E_) + schunk * 16;
  char* lA = (char*)As + wid * 1024;
  char* lB = (char*)Bs + wid * 1024;
  const int fr = lane & 15, kb = lane >> 4;

  f32x4 acc[4][4] = {};

  for (int kt = 0; kt < 32; ++kt) {
    gload_lds16(gA + kt * 64,              lA);
    gload_lds16(gA + kt * 64 + 64 * 2048,  lA + 4096);
    gload_lds16(gB + kt * 64,              lB);
    gload_lds16(gB + kt * 64 + 64 * 2048,  lB + 4096);
    __syncthreads();
    bf16x8 a[4], b[4];
#pragma unroll
    for (int m = 0; m < 4; ++m)
      a[m] = *(const bf16x8*)((const char*)As + (wr + m * 16 + fr) * 64 + kb * 16);
#pragma unroll
    for (int n = 0; n < 4; ++n)
      b[n] = *(const bf16x8*)((const char*)Bs + (wc + n * 16 + fr) * 64 + kb * 16);
#pragma unroll
    for (int m = 0; m < 4; ++m)
#pragma unroll
      for (int n = 0; n < 4; ++n)
        acc[m][n] = MFMA16(a[m], b[n], acc[m][n]);
    __syncthreads();
  }

  float bv[4];
#pragma unroll
  for (int n = 0; n < 4; ++n) bv[n] = bias[col0 + wc + n * 16 + fr];

  const int gate = col0 >> 10;             // 128-col tile spans one gate
  const int cg0  = (col0 & 1023) >> 5;     // first of 4 col-groups

#pragma unroll
  for (int h = 0; h < 2; ++h) {
    if ((wid >> 1) == h) {
#pragma unroll
      for (int m = 0; m < 4; ++m)
#pragma unroll
        for (int n = 0; n < 4; ++n)
#pragma unroll
          for (int r = 0; r < 4; ++r)
            eps[m * 16 + kb * 4 + r][wc + n * 16 + fr] = (__bf16)(acc[m][n][r] + bv[n]);
    }
    __syncthreads();
    {
      const int row = tid >> 2, ch = tid & 3;
      const int r_m = row0 + h * 64 + row;
      const uint4* s = (const uint4*)&eps[row][ch * 32];
      uint4* d = (uint4*)(XW2 + ((size_t)r_m * 32 + (cg0 + ch)) * 128 + gate * 32);
#pragma unroll
      for (int i = 0; i < 4; ++i) d[i] = s[i];
    }
    __syncthreads();
  }
}

// --------------------------------------------------- scan helpers (static idx)
__device__ __forceinline__ void load8(const __bf16* wb, int gbase, bf16x8 (&P)[8]) {
#pragma unroll
  for (int j = 0; j < 8; ++j)
    P[j] = *(const bf16x8*)(wb + (gbase + j) * 32);
}
__device__ __forceinline__ void mfma8(const char* Asb, int fr, int kb, int gbase,
                                      bf16x8 (&P)[8], f32x4& a0, f32x4& a1) {
#pragma unroll
  for (int j = 0; j < 8; ++j) {
    const int ck = (gbase + j) * 4 + kb;
    bf16x8 alo = *(const bf16x8*)(Asb + fr * 2048 + ((ck ^ (fr & 7)) * 16));
    bf16x8 ahi = *(const bf16x8*)(Asb + (16 + fr) * 2048 + ((ck ^ (fr & 7)) * 16));
    a0 = MFMA16(alo, P[j], a0);
    a1 = MFMA16(ahi, P[j], a1);
  }
}

// ----------------------------------------------------- persistent LSTM scan
// 256 blocks (1/CU), 512 threads. Block = 32 batch rows x 32 h-cols.
// Wave = (gate, col-half); both row-halves per wave (Wh reads deduped).
// Sync: bg-LOCAL barrier (32 blocks sharing batch rows), atomic store/poll.
__global__ __launch_bounds__(512, 1) void lstm_scan(
    const __bf16* __restrict__ WhT, const __bf16* __restrict__ XW2,
    __bf16* __restrict__ hb0, __bf16* __restrict__ hb1,
    float* __restrict__ outp, float* __restrict__ hfin,
    float* __restrict__ cfin, unsigned* __restrict__ flags) {
  __shared__ __bf16 As[32 * 1024];     // 64 KB, XOR-swizzled 16B chunks
  __shared__ float  zs[4][32][34];
  const int tid = threadIdx.x;
  const int lane = tid & 63;
  const int wid = tid >> 6;
  const int bid = blockIdx.x;
  const int bg = (bid >> 3) & 7;
  const int cg = (bid & 7) + (bid >> 6) * 8;   // XCD-affine col groups
  const int b0 = bg * 32;
  const int c0 = cg * 32;
  unsigned* grpflags = flags + bg * 64;        // 32 flags, 2 cachelines/group

  const int wg = wid & 3;      // gate (i,f,g,o)
  const int nh = wid >> 2;     // col half
  const int fr = lane & 15, kb = lane >> 4;
  const __bf16* wb = WhT + (size_t)(wg * 1024 + c0 + nh * 16 + fr) * H_ + kb * 8;

  const int crow = tid >> 4, ccolb = (tid & 15) * 2;
  const size_t sidx = (size_t)(b0 + crow) * H_ + c0 + ccolb;
  const __bf16* xwrow = XW2 + ((size_t)(b0 + crow) * S_ * 32 + cg) * 128 + ccolb;
  float creg0 = 0.f, creg1 = 0.f;

#pragma unroll 1
  for (int t = 0; t < S_; ++t) {
    const __bf16* hin = (t & 1) ? hb1 : hb0;
    __bf16* hout = (t & 1) ? hb0 : hb1;

    // XW cell inputs for step t (plain cached loads, issued early).
    const __bf16* p = xwrow + (size_t)t * 4096;
    const unsigned xw0 = *(const unsigned*)(p);
    const unsigned xw1 = *(const unsigned*)(p + 32);
    const unsigned xw2 = *(const unsigned*)(p + 64);
    const unsigned xw3 = *(const unsigned*)(p + 96);

    // ---- wait for h(t-1) of OUR bg group (32 producers) ----
    if (t > 0) {
      if (tid < 32) {
        const unsigned tgt = (unsigned)t;
        while (__hip_atomic_load(&grpflags[tid], __ATOMIC_RELAXED,
                                 __HIP_MEMORY_SCOPE_AGENT) < tgt)
          __builtin_amdgcn_s_sleep(1);
      }
      __syncthreads();
    }

    // ---- stage h rows [b0,b0+32): bypass loads -> swizzled ds_write ----
    {
      uint4 sv[8];
#pragma unroll
      for (int i = 0; i < 8; ++i) {
        const int ci = i * 512 + tid;
        const int row = ci >> 7, cch = ci & 127;
        const void* src = (const char*)(hin + (size_t)(b0 + row) * H_) + cch * 16;
        asm volatile("global_load_dwordx4 %0, %1, off sc0 sc1"
                     : "=&v"(sv[i]) : "v"(src) : "memory");
      }
      asm volatile("s_waitcnt vmcnt(0)" ::: "memory");
      __builtin_amdgcn_sched_barrier(0);
#pragma unroll
      for (int i = 0; i < 8; ++i) {
        const int ci = i * 512 + tid;
        const int row = ci >> 7, cch = ci & 127;
        *(uint4*)((char*)As + row * 2048 + ((cch ^ (row & 7)) * 16)) = sv[i];
      }
    }
    __syncthreads();

    // ---- MFMA: 32 rows x 16 cols per wave, Wh register double-buffer ----
    f32x4 acc0 = {0.f, 0.f, 0.f, 0.f}, acc1 = {0.f, 0.f, 0.f, 0.f};
    {
      bf16x8 P[8], Q[8];
      load8(wb, 0, P);
      load8(wb, 8, Q);
      mfma8((const char*)As, fr, kb, 0, P, acc0, acc1);
      load8(wb, 16, P);
      mfma8((const char*)As, fr, kb, 8, Q, acc0, acc1);
      load8(wb, 24, Q);
      mfma8((const char*)As, fr, kb, 16, P, acc0, acc1);
      mfma8((const char*)As, fr, kb, 24, Q, acc0, acc1);
    }
#pragma unroll
    for (int r = 0; r < 4; ++r) {
      zs[wg][kb * 4 + r][nh * 16 + fr]      = acc0[r];
      zs[wg][16 + kb * 4 + r][nh * 16 + fr] = acc1[r];
    }
    __syncthreads();

    // ---- cell (fp32), c in registers ----
    const float2 zi2 = *(const float2*)&zs[0][crow][ccolb];
    const float2 zf2 = *(const float2*)&zs[1][crow][ccolb];
    const float2 zg2 = *(const float2*)&zs[2][crow][ccolb];
    const float2 zo2 = *(const float2*)&zs[3][crow][ccolb];
    const float zi0 = zi2.x + bf_lo(xw0), zi1 = zi2.y + bf_hi(xw0);
    const float zf0 = zf2.x + bf_lo(xw1), zf1 = zf2.y + bf_hi(xw1);
    const float zg0 = zg2.x + bf_lo(xw2), zg1 = zg2.y + bf_hi(xw2);
    const float zo0 = zo2.x + bf_lo(xw3), zo1 = zo2.y + bf_hi(xw3);
    const float cv0 = sigm(zf0) * creg0 + sigm(zi0) * tanhfast(zg0);
    const float cv1 = sigm(zf1) * creg1 + sigm(zi1) * tanhfast(zg1);
    creg0 = cv0; creg1 = cv1;
    const float hv0 = sigm(zo0) * tanhfast(cv0);
    const float hv1 = sigm(zo1) * tanhfast(cv1);

    union { __bf16 h[2]; unsigned u; } up;
    up.h[0] = (__bf16)hv0; up.h[1] = (__bf16)hv1;
    float2 o2; o2.x = hv0; o2.y = hv1;

    // outputs: plain store for outp; sc0sc1 write-through for h
    *(float2*)(outp + ((size_t)(b0 + crow) * S_ + t) * H_ + c0 + ccolb) = o2;
    {
      void* dst = (void*)(hout + sidx);
      asm volatile("global_store_dword %0, %1, off sc0 sc1"
                   :: "v"(dst), "v"(up.u) : "memory");
    }

    if (t == S_ - 1) {
      float2 c2; c2.x = cv0; c2.y = cv1;
      *(float2*)(hfin + sidx) = o2;
      *(float2*)(cfin + sidx) = c2;
    } else {
      asm volatile("s_waitcnt vmcnt(0)" ::: "memory");   // drain h + outp
      __builtin_amdgcn_s_barrier();
      if (tid == 0)
        __hip_atomic_store(&grpflags[cg], (unsigned)(t + 1),
                           __ATOMIC_RELAXED, __HIP_MEMORY_SCOPE_AGENT);
    }
  }
}

// ----------------------------------------------------------------- launcher
extern "C" void kernel_launch(void* const* d_in, const int* in_sizes, int n_in,
                              void* d_out, int out_size, void* d_ws, size_t ws_size,
                              hipStream_t stream) {
  const int*   inp  = (const int*)d_in[0];
  const float* emb  = (const float*)d_in[1];
  const float* Wi   = (const float*)d_in[2];
  const float* Wh   = (const float*)d_in[3];
  const float* bias = (const float*)d_in[4];

  char* ws = (char*)d_ws;
  __bf16* WiT = (__bf16*)(ws);
  __bf16* WhT = (__bf16*)(ws + 8388608);
  __bf16* hb0 = (__bf16*)(ws + 16777216);
  __bf16* hb1 = (__bf16*)(ws + 17301504);
  __bf16* X   = (__bf16*)(ws + 17825792);
  __bf16* XW2 = (__bf16*)(ws + 152043520);
  unsigned* flags = (unsigned*)(ws + 17825792);  // overlays dead X during scan

  float* outp = (float*)d_out;
  float* hfin = outp + (size_t)M_ * H_;
  float* cfin = hfin + (size_t)B_ * H_;

  zero_init<<<128, 256, 0, stream>>>((uint4*)hb0);
  transpose_cast<<<dim3(128, 32), 256, 0, stream>>>(Wi, WiT);
  transpose_cast<<<dim3(128, 32), 256, 0, stream>>>(Wh, WhT);
  gather_cast<<<32768, 256, 0, stream>>>(inp, emb, X);
  gemm_xw<<<16384, 256, 0, stream>>>(X, WiT, bias, XW2);
  zero_flags<<<2, 256, 0, stream>>>(flags);   // X is dead from here on
  lstm_scan<<<256, 512, 0, stream>>>(WhT, XW2, hb0, hb1, outp, hfin, cfin, flags);
}

// Round 8
// 2160.610 us; speedup vs baseline: 4.1054x; 1.6223x over previous
//
#include <hip/hip_runtime.h>
#include <hip/hip_bf16.h>
#include <stdint.h>

// EncoderFLAX: x = emb[inputs]; xW = x@Wi + b; LSTM scan over S with Wh.
// B=256 S=256 V=32000 E=1024 H=1024. Outputs: [B,S,H] fp32, h [B,H], c [B,H].
//
// Round 8 = round 7 + Wh register-resident (main change):
//   each wave's B-slice (16 cols x 1024 K bf16 = 128 VGPR/lane) is loaded
//   ONCE before the t-loop and reused for all 256 steps -> zero steady-state
//   Wh L2 traffic (was 256KB/block/step ~= 1.9us/step on the serial path).
//   Fully-unrolled static W[32] indexing; __launch_bounds__(512,2) pins the
//   256-VGPR cap (8 waves/CU unchanged — LDS already limits to 1 block/CU).
// Also: outp stores moved AFTER the flag store (pre-flag vmcnt(0) drains only
//   the 4B h-store; outp has a full step of slack, nothing reads it).
// Round 7 proven parts unchanged: bg-local flags (atomic store/poll),
// sc0sc1 h write-through + bypass staging, (gate,col-half) waves, XW2 layout.
//
// ws layout (bytes):
//   WiT 0..8388608, WhT ..16777216, hb0 ..17301504, hb1 ..17825792,
//   X ..152043520 (first 2KB reused as barrier flags during the scan),
//   XW ..688914432

#define B_ 256
#define S_ 256
#define E_ 1024
#define H_ 1024
#define G_ 4096
#define M_ 65536

typedef float  f32x4  __attribute__((ext_vector_type(4)));
typedef __bf16 bf16x8 __attribute__((ext_vector_type(8)));

#define MFMA16(a, b, c) __builtin_amdgcn_mfma_f32_16x16x32_bf16((a), (b), (c), 0, 0, 0)

__device__ __forceinline__ void gload_lds16(const void* g, void* l) {
  __builtin_amdgcn_global_load_lds(
      (__attribute__((address_space(1))) void*)(g),
      (__attribute__((address_space(3))) void*)(l), 16, 0, 0);
}

__device__ __forceinline__ float sigm(float x) { return 1.f / (1.f + __expf(-x)); }
__device__ __forceinline__ float tanhfast(float x) {
  float e = __expf(-2.f * x);
  return (1.f - e) / (1.f + e);
}
__device__ __forceinline__ float bf_lo(unsigned v) { return __uint_as_float(v << 16); }
__device__ __forceinline__ float bf_hi(unsigned v) { return __uint_as_float(v & 0xffff0000u); }

// ---------------------------------------------------------------- zero init
__global__ __launch_bounds__(256) void zero_init(uint4* h16) {
  int i = blockIdx.x * 256 + threadIdx.x;
  uint4 z; z.x = z.y = z.z = z.w = 0u;
  if (i < 32768) h16[i] = z;            // hb0: 262144 bf16 = 32768 x 16B
}
__global__ __launch_bounds__(256) void zero_flags(unsigned* flags) {
  flags[blockIdx.x * 256 + threadIdx.x] = 0u;   // 512 dwords
}

// ------------------------------------------------- transpose+cast [1024][4096]
__global__ __launch_bounds__(256) void transpose_cast(const float* __restrict__ in,
                                                      __bf16* __restrict__ out) {
  __shared__ __bf16 tile[32][33];
  const int c0 = blockIdx.x * 32;
  const int r0 = blockIdx.y * 32;
  const int tx = threadIdx.x & 31, ty = threadIdx.x >> 5;
#pragma unroll
  for (int p = 0; p < 4; ++p) {
    const int rr = ty + p * 8;
    tile[rr][tx] = (__bf16)in[(size_t)(r0 + rr) * G_ + c0 + tx];
  }
  __syncthreads();
#pragma unroll
  for (int p = 0; p < 4; ++p) {
    const int rr = ty + p * 8;
    out[(size_t)(c0 + rr) * E_ + r0 + tx] = tile[tx][rr];
  }
}

// ------------------------------------------------------- embedding gather+cast
union U16b { uint4 v; __bf16 h[8]; };
__global__ __launch_bounds__(256) void gather_cast(const int* __restrict__ idx,
                                                   const float* __restrict__ emb,
                                                   __bf16* __restrict__ X) {
  const size_t gid  = (size_t)blockIdx.x * 256 + threadIdx.x;
  const size_t base = gid * 8;
  const int r = (int)(base >> 10);
  const int e = (int)(base & 1023);
  const int row = idx[r];
  const float4* s = (const float4*)(emb + (size_t)row * E_ + e);
  const float4 v0 = s[0], v1 = s[1];
  U16b u;
  u.h[0] = (__bf16)v0.x; u.h[1] = (__bf16)v0.y; u.h[2] = (__bf16)v0.z; u.h[3] = (__bf16)v0.w;
  u.h[4] = (__bf16)v1.x; u.h[5] = (__bf16)v1.y; u.h[6] = (__bf16)v1.z; u.h[7] = (__bf16)v1.w;
  *(uint4*)(X + base) = u.v;
}

// --------------------------------------------------- xW GEMM (m97 structure)
// Writes XW PERMUTED: elem offset = ((row*32 + cg)*4 + gate)*32 + col_in_cg.
__global__ __launch_bounds__(256) void gemm_xw(const __bf16* __restrict__ X,
                                               const __bf16* __restrict__ WiT,
                                               const float* __restrict__ bias,
                                               __bf16* __restrict__ XW2) {
  __shared__ __bf16 As[128 * 32];
  __shared__ __bf16 Bs[128 * 32];
  __shared__ __bf16 eps[64][136];
  const int tid = threadIdx.x;
  const int lane = tid & 63;
  const int wid = tid >> 6;
  const int bn = blockIdx.x & 31;
  const int bm = blockIdx.x >> 5;
  const int row0 = bm * 128, col0 = bn * 128;
  const int wr = (wid >> 1) * 64, wc = (wid & 1) * 64;
  const int srow = tid >> 2, schunk = tid & 3;
  const char* gA = (const char*)(X + (size_t)(row0 + srow) * E_) + schunk * 16;
  const char* gB = (const char*)(WiT + (size_t)(col0 + srow) * E_) + schunk * 16;
  char* lA = (char*)As + wid * 1024;
  char* lB = (char*)Bs + wid * 1024;
  const int fr = lane & 15, kb = lane >> 4;

  f32x4 acc[4][4] = {};

  for (int kt = 0; kt < 32; ++kt) {
    gload_lds16(gA + kt * 64,              lA);
    gload_lds16(gA + kt * 64 + 64 * 2048,  lA + 4096);
    gload_lds16(gB + kt * 64,              lB);
    gload_lds16(gB + kt * 64 + 64 * 2048,  lB + 4096);
    __syncthreads();
    bf16x8 a[4], b[4];
#pragma unroll
    for (int m = 0; m < 4; ++m)
      a[m] = *(const bf16x8*)((const char*)As + (wr + m * 16 + fr) * 64 + kb * 16);
#pragma unroll
    for (int n = 0; n < 4; ++n)
      b[n] = *(const bf16x8*)((const char*)Bs + (wc + n * 16 + fr) * 64 + kb * 16);
#pragma unroll
    for (int m = 0; m < 4; ++m)
#pragma unroll
      for (int n = 0; n < 4; ++n)
        acc[m][n] = MFMA16(a[m], b[n], acc[m][n]);
    __syncthreads();
  }

  float bv[4];
#pragma unroll
  for (int n = 0; n < 4; ++n) bv[n] = bias[col0 + wc + n * 16 + fr];

  const int gate = col0 >> 10;             // 128-col tile spans one gate
  const int cg0  = (col0 & 1023) >> 5;     // first of 4 col-groups

#pragma unroll
  for (int h = 0; h < 2; ++h) {
    if ((wid >> 1) == h) {
#pragma unroll
      for (int m = 0; m < 4; ++m)
#pragma unroll
        for (int n = 0; n < 4; ++n)
#pragma unroll
          for (int r = 0; r < 4; ++r)
            eps[m * 16 + kb * 4 + r][wc + n * 16 + fr] = (__bf16)(acc[m][n][r] + bv[n]);
    }
    __syncthreads();
    {
      const int row = tid >> 2, ch = tid & 3;
      const int r_m = row0 + h * 64 + row;
      const uint4* s = (const uint4*)&eps[row][ch * 32];
      uint4* d = (uint4*)(XW2 + ((size_t)r_m * 32 + (cg0 + ch)) * 128 + gate * 32);
#pragma unroll
      for (int i = 0; i < 4; ++i) d[i] = s[i];
    }
    __syncthreads();
  }
}

// ----------------------------------------------------- persistent LSTM scan
// 256 blocks (1/CU), 512 threads. Block = 32 batch rows x 32 h-cols.
// Wave = (gate, col-half); both row-halves per wave. Wh REGISTER-RESIDENT
// (W[32] bf16x8 = 128 VGPR/lane, loaded once). bg-local barrier.
__global__ __launch_bounds__(512, 2) void lstm_scan(
    const __bf16* __restrict__ WhT, const __bf16* __restrict__ XW2,
    __bf16* __restrict__ hb0, __bf16* __restrict__ hb1,
    float* __restrict__ outp, float* __restrict__ hfin,
    float* __restrict__ cfin, unsigned* __restrict__ flags) {
  __shared__ __bf16 As[32 * 1024];     // 64 KB, XOR-swizzled 16B chunks
  __shared__ float  zs[4][32][34];
  const int tid = threadIdx.x;
  const int lane = tid & 63;
  const int wid = tid >> 6;
  const int bid = blockIdx.x;
  const int bg = (bid >> 3) & 7;
  const int cg = (bid & 7) + (bid >> 6) * 8;   // XCD-affine col groups
  const int b0 = bg * 32;
  const int c0 = cg * 32;
  unsigned* grpflags = flags + bg * 64;        // 32 flags, 2 cachelines/group

  const int wg = wid & 3;      // gate (i,f,g,o)
  const int nh = wid >> 2;     // col half
  const int fr = lane & 15, kb = lane >> 4;
  const __bf16* wb = WhT + (size_t)(wg * 1024 + c0 + nh * 16 + fr) * H_ + kb * 8;

  // ---- Wh slice -> registers, once (static full-unroll indexing) ----
  bf16x8 W[32];
#pragma unroll
  for (int j = 0; j < 32; ++j) W[j] = *(const bf16x8*)(wb + j * 32);

  const int crow = tid >> 4, ccolb = (tid & 15) * 2;
  const size_t sidx = (size_t)(b0 + crow) * H_ + c0 + ccolb;
  const __bf16* xwrow = XW2 + ((size_t)(b0 + crow) * S_ * 32 + cg) * 128 + ccolb;
  float creg0 = 0.f, creg1 = 0.f;

#pragma unroll 1
  for (int t = 0; t < S_; ++t) {
    const __bf16* hin = (t & 1) ? hb1 : hb0;
    __bf16* hout = (t & 1) ? hb0 : hb1;

    // XW cell inputs for step t (plain cached loads, issued early).
    const __bf16* p = xwrow + (size_t)t * 4096;
    const unsigned xw0 = *(const unsigned*)(p);
    const unsigned xw1 = *(const unsigned*)(p + 32);
    const unsigned xw2 = *(const unsigned*)(p + 64);
    const unsigned xw3 = *(const unsigned*)(p + 96);

    // ---- wait for h(t-1) of OUR bg group (32 producers) ----
    if (t > 0) {
      if (tid < 32) {
        const unsigned tgt = (unsigned)t;
        while (__hip_atomic_load(&grpflags[tid], __ATOMIC_RELAXED,
                                 __HIP_MEMORY_SCOPE_AGENT) < tgt)
          __builtin_amdgcn_s_sleep(1);
      }
      __syncthreads();
    }

    // ---- stage h rows [b0,b0+32): bypass loads -> swizzled ds_write ----
    {
      uint4 sv[8];
#pragma unroll
      for (int i = 0; i < 8; ++i) {
        const int ci = i * 512 + tid;
        const int row = ci >> 7, cch = ci & 127;
        const void* src = (const char*)(hin + (size_t)(b0 + row) * H_) + cch * 16;
        asm volatile("global_load_dwordx4 %0, %1, off sc0 sc1"
                     : "=&v"(sv[i]) : "v"(src) : "memory");
      }
      asm volatile("s_waitcnt vmcnt(0)" ::: "memory");
      __builtin_amdgcn_sched_barrier(0);
#pragma unroll
      for (int i = 0; i < 8; ++i) {
        const int ci = i * 512 + tid;
        const int row = ci >> 7, cch = ci & 127;
        *(uint4*)((char*)As + row * 2048 + ((cch ^ (row & 7)) * 16)) = sv[i];
      }
    }
    __syncthreads();

    // ---- MFMA: 32 rows x 16 cols per wave, Wh from registers ----
    f32x4 acc0 = {0.f, 0.f, 0.f, 0.f}, acc1 = {0.f, 0.f, 0.f, 0.f};
#pragma unroll
    for (int j = 0; j < 32; ++j) {
      const int ck = j * 4 + kb;
      bf16x8 alo = *(const bf16x8*)((const char*)As + fr * 2048 +
                                    ((ck ^ (fr & 7)) * 16));
      bf16x8 ahi = *(const bf16x8*)((const char*)As + (16 + fr) * 2048 +
                                    ((ck ^ (fr & 7)) * 16));
      acc0 = MFMA16(alo, W[j], acc0);
      acc1 = MFMA16(ahi, W[j], acc1);
    }
#pragma unroll
    for (int r = 0; r < 4; ++r) {
      zs[wg][kb * 4 + r][nh * 16 + fr]      = acc0[r];
      zs[wg][16 + kb * 4 + r][nh * 16 + fr] = acc1[r];
    }
    __syncthreads();

    // ---- cell (fp32), c in registers ----
    const float2 zi2 = *(const float2*)&zs[0][crow][ccolb];
    const float2 zf2 = *(const float2*)&zs[1][crow][ccolb];
    const float2 zg2 = *(const float2*)&zs[2][crow][ccolb];
    const float2 zo2 = *(const float2*)&zs[3][crow][ccolb];
    const float zi0 = zi2.x + bf_lo(xw0), zi1 = zi2.y + bf_hi(xw0);
    const float zf0 = zf2.x + bf_lo(xw1), zf1 = zf2.y + bf_hi(xw1);
    const float zg0 = zg2.x + bf_lo(xw2), zg1 = zg2.y + bf_hi(xw2);
    const float zo0 = zo2.x + bf_lo(xw3), zo1 = zo2.y + bf_hi(xw3);
    const float cv0 = sigm(zf0) * creg0 + sigm(zi0) * tanhfast(zg0);
    const float cv1 = sigm(zf1) * creg1 + sigm(zi1) * tanhfast(zg1);
    creg0 = cv0; creg1 = cv1;
    const float hv0 = sigm(zo0) * tanhfast(cv0);
    const float hv1 = sigm(zo1) * tanhfast(cv1);

    union { __bf16 h[2]; unsigned u; } up;
    up.h[0] = (__bf16)hv0; up.h[1] = (__bf16)hv1;
    float2 o2; o2.x = hv0; o2.y = hv1;

    // h store (release payload, write-through)
    {
      void* dst = (void*)(hout + sidx);
      asm volatile("global_store_dword %0, %1, off sc0 sc1"
                   :: "v"(dst), "v"(up.u) : "memory");
    }

    if (t == S_ - 1) {
      *(float2*)(outp + ((size_t)(b0 + crow) * S_ + t) * H_ + c0 + ccolb) = o2;
      float2 c2; c2.x = cv0; c2.y = cv1;
      *(float2*)(hfin + sidx) = o2;
      *(float2*)(cfin + sidx) = c2;
    } else {
      asm volatile("s_waitcnt vmcnt(0)" ::: "memory");   // drain h store only
      __builtin_amdgcn_s_barrier();
      if (tid == 0)
        __hip_atomic_store(&grpflags[cg], (unsigned)(t + 1),
                           __ATOMIC_RELAXED, __HIP_MEMORY_SCOPE_AGENT);
      // outp store AFTER the flag: a full step of slack to drain; not consumed
      *(float2*)(outp + ((size_t)(b0 + crow) * S_ + t) * H_ + c0 + ccolb) = o2;
    }
  }
}

// ----------------------------------------------------------------- launcher
extern "C" void kernel_launch(void* const* d_in, const int* in_sizes, int n_in,
                              void* d_out, int out_size, void* d_ws, size_t ws_size,
                              hipStream_t stream) {
  const int*   inp  = (const int*)d_in[0];
  const float* emb  = (const float*)d_in[1];
  const float* Wi   = (const float*)d_in[2];
  const float* Wh   = (const float*)d_in[3];
  const float* bias = (const float*)d_in[4];

  char* ws = (char*)d_ws;
  __bf16* WiT = (__bf16*)(ws);
  __bf16* WhT = (__bf16*)(ws + 8388608);
  __bf16* hb0 = (__bf16*)(ws + 16777216);
  __bf16* hb1 = (__bf16*)(ws + 17301504);
  __bf16* X   = (__bf16*)(ws + 17825792);
  __bf16* XW2 = (__bf16*)(ws + 152043520);
  unsigned* flags = (unsigned*)(ws + 17825792);  // overlays dead X during scan

  float* outp = (float*)d_out;
  float* hfin = outp + (size_t)M_ * H_;
  float* cfin = hfin + (size_t)B_ * H_;

  zero_init<<<128, 256, 0, stream>>>((uint4*)hb0);
  transpose_cast<<<dim3(128, 32), 256, 0, stream>>>(Wi, WiT);
  transpose_cast<<<dim3(128, 32), 256, 0, stream>>>(Wh, WhT);
  gather_cast<<<32768, 256, 0, stream>>>(inp, emb, X);
  gemm_xw<<<16384, 256, 0, stream>>>(X, WiT, bias, XW2);
  zero_flags<<<2, 256, 0, stream>>>(flags);   // X is dead from here on
  lstm_scan<<<256, 512, 0, stream>>>(WhT, XW2, hb0, hb1, outp, hfin, cfin, flags);
}

// Round 9
// 2086.894 us; speedup vs baseline: 4.2504x; 1.0353x over previous
//
#include <hip/hip_runtime.h>
#include <hip/hip_bf16.h>
#include <stdint.h>

// EncoderFLAX: x = emb[inputs]; xW = x@Wi + b; LSTM scan over S with Wh.
// B=256 S=256 V=32000 E=1024 H=1024. Outputs: [B,S,H] fp32, h [B,H], c [B,H].
//
// Round 9 = round 8 + XCD-local h exchange (main change):
//   bg group == physical XCD, discovered at runtime: each block reads
//   HW_REG_XCC_ID (m09-verified) and grabs slot=fetch_add(cnt[xcd]) ->
//   (bg=xcd, cg=slot). Grid=256 with 1 block/CU (83KB LDS) => exactly 32
//   blocks/XCD, groups complete by construction (no dispatch assumptions).
//   h stores/loads become sc0-ONLY: write-through to the group's own L2,
//   loads bypass L1 and hit the same L2 (~0.2-0.3us vs ~0.6-0.9us MALL,
//   and 2MB/step/XCD at L2 BW instead of 16MB/step at MALL).
//   Flags stay agent-scope atomics at MALL (r6-proven mechanism, unchanged).
//   t=0 h zeros + XW reach consumers via kernel-boundary flush (MALL).
// Round 8 frozen parts: Wh register-resident W[32], bg-local flags,
// (gate,col-half) waves, permuted XW2, outp store after flag.
//
// ws layout (bytes):
//   WiT 0..8388608, WhT ..16777216, hb0 ..17301504, hb1 ..17825792,
//   X ..152043520 (first 4KB reused: [0..511] group flags, [512..519]
//   xcd slot counters — zeroed by zero_flags each launch), XW ..688914432

#define B_ 256
#define S_ 256
#define E_ 1024
#define H_ 1024
#define G_ 4096
#define M_ 65536

typedef float  f32x4  __attribute__((ext_vector_type(4)));
typedef __bf16 bf16x8 __attribute__((ext_vector_type(8)));

#define MFMA16(a, b, c) __builtin_amdgcn_mfma_f32_16x16x32_bf16((a), (b), (c), 0, 0, 0)

__device__ __forceinline__ void gload_lds16(const void* g, void* l) {
  __builtin_amdgcn_global_load_lds(
      (__attribute__((address_space(1))) void*)(g),
      (__attribute__((address_space(3))) void*)(l), 16, 0, 0);
}

__device__ __forceinline__ float sigm(float x) { return 1.f / (1.f + __expf(-x)); }
__device__ __forceinline__ float tanhfast(float x) {
  float e = __expf(-2.f * x);
  return (1.f - e) / (1.f + e);
}
__device__ __forceinline__ float bf_lo(unsigned v) { return __uint_as_float(v << 16); }
__device__ __forceinline__ float bf_hi(unsigned v) { return __uint_as_float(v & 0xffff0000u); }

// ---------------------------------------------------------------- zero init
__global__ __launch_bounds__(256) void zero_init(uint4* h16) {
  int i = blockIdx.x * 256 + threadIdx.x;
  uint4 z; z.x = z.y = z.z = z.w = 0u;
  if (i < 32768) h16[i] = z;            // hb0: 262144 bf16 = 32768 x 16B
}
__global__ __launch_bounds__(256) void zero_flags(unsigned* flags) {
  flags[blockIdx.x * 256 + threadIdx.x] = 0u;   // 1024 dwords (flags+counters)
}

// ------------------------------------------------- transpose+cast [1024][4096]
__global__ __launch_bounds__(256) void transpose_cast(const float* __restrict__ in,
                                                      __bf16* __restrict__ out) {
  __shared__ __bf16 tile[32][33];
  const int c0 = blockIdx.x * 32;
  const int r0 = blockIdx.y * 32;
  const int tx = threadIdx.x & 31, ty = threadIdx.x >> 5;
#pragma unroll
  for (int p = 0; p < 4; ++p) {
    const int rr = ty + p * 8;
    tile[rr][tx] = (__bf16)in[(size_t)(r0 + rr) * G_ + c0 + tx];
  }
  __syncthreads();
#pragma unroll
  for (int p = 0; p < 4; ++p) {
    const int rr = ty + p * 8;
    out[(size_t)(c0 + rr) * E_ + r0 + tx] = tile[tx][rr];
  }
}

// ------------------------------------------------------- embedding gather+cast
union U16b { uint4 v; __bf16 h[8]; };
__global__ __launch_bounds__(256) void gather_cast(const int* __restrict__ idx,
                                                   const float* __restrict__ emb,
                                                   __bf16* __restrict__ X) {
  const size_t gid  = (size_t)blockIdx.x * 256 + threadIdx.x;
  const size_t base = gid * 8;
  const int r = (int)(base >> 10);
  const int e = (int)(base & 1023);
  const int row = idx[r];
  const float4* s = (const float4*)(emb + (size_t)row * E_ + e);
  const float4 v0 = s[0], v1 = s[1];
  U16b u;
  u.h[0] = (__bf16)v0.x; u.h[1] = (__bf16)v0.y; u.h[2] = (__bf16)v0.z; u.h[3] = (__bf16)v0.w;
  u.h[4] = (__bf16)v1.x; u.h[5] = (__bf16)v1.y; u.h[6] = (__bf16)v1.z; u.h[7] = (__bf16)v1.w;
  *(uint4*)(X + base) = u.v;
}

// --------------------------------------------------- xW GEMM (m97 structure)
// Writes XW PERMUTED: elem offset = ((row*32 + cg)*4 + gate)*32 + col_in_cg.
__global__ __launch_bounds__(256) void gemm_xw(const __bf16* __restrict__ X,
                                               const __bf16* __restrict__ WiT,
                                               const float* __restrict__ bias,
                                               __bf16* __restrict__ XW2) {
  __shared__ __bf16 As[128 * 32];
  __shared__ __bf16 Bs[128 * 32];
  __shared__ __bf16 eps[64][136];
  const int tid = threadIdx.x;
  const int lane = tid & 63;
  const int wid = tid >> 6;
  const int bn = blockIdx.x & 31;
  const int bm = blockIdx.x >> 5;
  const int row0 = bm * 128, col0 = bn * 128;
  const int wr = (wid >> 1) * 64, wc = (wid & 1) * 64;
  const int srow = tid >> 2, schunk = tid & 3;
  const char* gA = (const char*)(X + (size_t)(row0 + srow) * E_) + schunk * 16;
  const char* gB = (const char*)(WiT + (size_t)(col0 + srow) * E_) + schunk * 16;
  char* lA = (char*)As + wid * 1024;
  char* lB = (char*)Bs + wid * 1024;
  const int fr = lane & 15, kb = lane >> 4;

  f32x4 acc[4][4] = {};

  for (int kt = 0; kt < 32; ++kt) {
    gload_lds16(gA + kt * 64,              lA);
    gload_lds16(gA + kt * 64 + 64 * 2048,  lA + 4096);
    gload_lds16(gB + kt * 64,              lB);
    gload_lds16(gB + kt * 64 + 64 * 2048,  lB + 4096);
    __syncthreads();
    bf16x8 a[4], b[4];
#pragma unroll
    for (int m = 0; m < 4; ++m)
      a[m] = *(const bf16x8*)((const char*)As + (wr + m * 16 + fr) * 64 + kb * 16);
#pragma unroll
    for (int n = 0; n < 4; ++n)
      b[n] = *(const bf16x8*)((const char*)Bs + (wc + n * 16 + fr) * 64 + kb * 16);
#pragma unroll
    for (int m = 0; m < 4; ++m)
#pragma unroll
      for (int n = 0; n < 4; ++n)
        acc[m][n] = MFMA16(a[m], b[n], acc[m][n]);
    __syncthreads();
  }

  float bv[4];
#pragma unroll
  for (int n = 0; n < 4; ++n) bv[n] = bias[col0 + wc + n * 16 + fr];

  const int gate = col0 >> 10;             // 128-col tile spans one gate
  const int cg0  = (col0 & 1023) >> 5;     // first of 4 col-groups

#pragma unroll
  for (int h = 0; h < 2; ++h) {
    if ((wid >> 1) == h) {
#pragma unroll
      for (int m = 0; m < 4; ++m)
#pragma unroll
        for (int n = 0; n < 4; ++n)
#pragma unroll
          for (int r = 0; r < 4; ++r)
            eps[m * 16 + kb * 4 + r][wc + n * 16 + fr] = (__bf16)(acc[m][n][r] + bv[n]);
    }
    __syncthreads();
    {
      const int row = tid >> 2, ch = tid & 3;
      const int r_m = row0 + h * 64 + row;
      const uint4* s = (const uint4*)&eps[row][ch * 32];
      uint4* d = (uint4*)(XW2 + ((size_t)r_m * 32 + (cg0 + ch)) * 128 + gate * 32);
#pragma unroll
      for (int i = 0; i < 4; ++i) d[i] = s[i];
    }
    __syncthreads();
  }
}

// ----------------------------------------------------- persistent LSTM scan
// 256 blocks (1/CU), 512 threads. Block = 32 batch rows x 32 h-cols.
// bg group == XCD (runtime-discovered); h exchange through the group's L2.
__global__ __launch_bounds__(512, 2) void lstm_scan(
    const __bf16* __restrict__ WhT, const __bf16* __restrict__ XW2,
    __bf16* __restrict__ hb0, __bf16* __restrict__ hb1,
    float* __restrict__ outp, float* __restrict__ hfin,
    float* __restrict__ cfin, unsigned* __restrict__ flags) {
  __shared__ __bf16 As[32 * 1024];     // 64 KB, XOR-swizzled 16B chunks
  __shared__ float  zs[4][32][34];
  __shared__ int    sgrp[2];
  const int tid = threadIdx.x;
  const int lane = tid & 63;
  const int wid = tid >> 6;

  // ---- runtime XCD grouping: bg = XCC_ID, cg = slot within the XCD ----
  if (tid == 0) {
    unsigned xcd;
    asm volatile("s_getreg_b32 %0, hwreg(HW_REG_XCC_ID)" : "=s"(xcd));
    xcd &= 7u;
    unsigned slot = __hip_atomic_fetch_add(&flags[512 + xcd], 1u,
                                           __ATOMIC_RELAXED, __HIP_MEMORY_SCOPE_AGENT);
    sgrp[0] = (int)xcd;
    sgrp[1] = (int)(slot & 31u);
  }
  __syncthreads();
  const int bg = sgrp[0];
  const int cg = sgrp[1];
  const int b0 = bg * 32;
  const int c0 = cg * 32;
  unsigned* grpflags = flags + bg * 64;        // 32 flags, 2 cachelines/group

  const int wg = wid & 3;      // gate (i,f,g,o)
  const int nh = wid >> 2;     // col half
  const int fr = lane & 15, kb = lane >> 4;
  const __bf16* wb = WhT + (size_t)(wg * 1024 + c0 + nh * 16 + fr) * H_ + kb * 8;

  // ---- Wh slice -> registers, once (static full-unroll indexing) ----
  bf16x8 W[32];
#pragma unroll
  for (int j = 0; j < 32; ++j) W[j] = *(const bf16x8*)(wb + j * 32);

  const int crow = tid >> 4, ccolb = (tid & 15) * 2;
  const size_t sidx = (size_t)(b0 + crow) * H_ + c0 + ccolb;
  const __bf16* xwrow = XW2 + ((size_t)(b0 + crow) * S_ * 32 + cg) * 128 + ccolb;
  float creg0 = 0.f, creg1 = 0.f;

#pragma unroll 1
  for (int t = 0; t < S_; ++t) {
    const __bf16* hin = (t & 1) ? hb1 : hb0;
    __bf16* hout = (t & 1) ? hb0 : hb1;

    // XW cell inputs for step t (plain cached loads, issued early).
    const __bf16* p = xwrow + (size_t)t * 4096;
    const unsigned xw0 = *(const unsigned*)(p);
    const unsigned xw1 = *(const unsigned*)(p + 32);
    const unsigned xw2 = *(const unsigned*)(p + 64);
    const unsigned xw3 = *(const unsigned*)(p + 96);

    // ---- wait for h(t-1) of OUR bg group (32 same-XCD producers) ----
    if (t > 0) {
      if (tid < 32) {
        const unsigned tgt = (unsigned)t;
        while (__hip_atomic_load(&grpflags[tid], __ATOMIC_RELAXED,
                                 __HIP_MEMORY_SCOPE_AGENT) < tgt)
          __builtin_amdgcn_s_sleep(1);
      }
      __syncthreads();
    }

    // ---- stage h rows [b0,b0+32): sc0-only loads (own-XCD L2 hit) ----
    {
      uint4 sv[8];
#pragma unroll
      for (int i = 0; i < 8; ++i) {
        const int ci = i * 512 + tid;
        const int row = ci >> 7, cch = ci & 127;
        const void* src = (const char*)(hin + (size_t)(b0 + row) * H_) + cch * 16;
        asm volatile("global_load_dwordx4 %0, %1, off sc0"
                     : "=&v"(sv[i]) : "v"(src) : "memory");
      }
      asm volatile("s_waitcnt vmcnt(0)" ::: "memory");
      __builtin_amdgcn_sched_barrier(0);
#pragma unroll
      for (int i = 0; i < 8; ++i) {
        const int ci = i * 512 + tid;
        const int row = ci >> 7, cch = ci & 127;
        *(uint4*)((char*)As + row * 2048 + ((cch ^ (row & 7)) * 16)) = sv[i];
      }
    }
    __syncthreads();

    // ---- MFMA: 32 rows x 16 cols per wave, Wh from registers ----
    f32x4 acc0 = {0.f, 0.f, 0.f, 0.f}, acc1 = {0.f, 0.f, 0.f, 0.f};
#pragma unroll
    for (int j = 0; j < 32; ++j) {
      const int ck = j * 4 + kb;
      bf16x8 alo = *(const bf16x8*)((const char*)As + fr * 2048 +
                                    ((ck ^ (fr & 7)) * 16));
      bf16x8 ahi = *(const bf16x8*)((const char*)As + (16 + fr) * 2048 +
                                    ((ck ^ (fr & 7)) * 16));
      acc0 = MFMA16(alo, W[j], acc0);
      acc1 = MFMA16(ahi, W[j], acc1);
    }
#pragma unroll
    for (int r = 0; r < 4; ++r) {
      zs[wg][kb * 4 + r][nh * 16 + fr]      = acc0[r];
      zs[wg][16 + kb * 4 + r][nh * 16 + fr] = acc1[r];
    }
    __syncthreads();

    // ---- cell (fp32), c in registers ----
    const float2 zi2 = *(const float2*)&zs[0][crow][ccolb];
    const float2 zf2 = *(const float2*)&zs[1][crow][ccolb];
    const float2 zg2 = *(const float2*)&zs[2][crow][ccolb];
    const float2 zo2 = *(const float2*)&zs[3][crow][ccolb];
    const float zi0 = zi2.x + bf_lo(xw0), zi1 = zi2.y + bf_hi(xw0);
    const float zf0 = zf2.x + bf_lo(xw1), zf1 = zf2.y + bf_hi(xw1);
    const float zg0 = zg2.x + bf_lo(xw2), zg1 = zg2.y + bf_hi(xw2);
    const float zo0 = zo2.x + bf_lo(xw3), zo1 = zo2.y + bf_hi(xw3);
    const float cv0 = sigm(zf0) * creg0 + sigm(zi0) * tanhfast(zg0);
    const float cv1 = sigm(zf1) * creg1 + sigm(zi1) * tanhfast(zg1);
    creg0 = cv0; creg1 = cv1;
    const float hv0 = sigm(zo0) * tanhfast(cv0);
    const float hv1 = sigm(zo1) * tanhfast(cv1);

    union { __bf16 h[2]; unsigned u; } up;
    up.h[0] = (__bf16)hv0; up.h[1] = (__bf16)hv1;
    float2 o2; o2.x = hv0; o2.y = hv1;

    // h store: sc0-only -> lands in our XCD's L2 (consumers are same-XCD)
    {
      void* dst = (void*)(hout + sidx);
      asm volatile("global_store_dword %0, %1, off sc0"
                   :: "v"(dst), "v"(up.u) : "memory");
    }

    if (t == S_ - 1) {
      *(float2*)(outp + ((size_t)(b0 + crow) * S_ + t) * H_ + c0 + ccolb) = o2;
      float2 c2; c2.x = cv0; c2.y = cv1;
      *(float2*)(hfin + sidx) = o2;
      *(float2*)(cfin + sidx) = c2;
    } else {
      asm volatile("s_waitcnt vmcnt(0)" ::: "memory");   // h committed to L2
      __builtin_amdgcn_s_barrier();
      if (tid == 0)
        __hip_atomic_store(&grpflags[cg], (unsigned)(t + 1),
                           __ATOMIC_RELAXED, __HIP_MEMORY_SCOPE_AGENT);
      // outp store AFTER the flag: a full step of slack to drain
      *(float2*)(outp + ((size_t)(b0 + crow) * S_ + t) * H_ + c0 + ccolb) = o2;
    }
  }
}

// ----------------------------------------------------------------- launcher
extern "C" void kernel_launch(void* const* d_in, const int* in_sizes, int n_in,
                              void* d_out, int out_size, void* d_ws, size_t ws_size,
                              hipStream_t stream) {
  const int*   inp  = (const int*)d_in[0];
  const float* emb  = (const float*)d_in[1];
  const float* Wi   = (const float*)d_in[2];
  const float* Wh   = (const float*)d_in[3];
  const float* bias = (const float*)d_in[4];

  char* ws = (char*)d_ws;
  __bf16* WiT = (__bf16*)(ws);
  __bf16* WhT = (__bf16*)(ws + 8388608);
  __bf16* hb0 = (__bf16*)(ws + 16777216);
  __bf16* hb1 = (__bf16*)(ws + 17301504);
  __bf16* X   = (__bf16*)(ws + 17825792);
  __bf16* XW2 = (__bf16*)(ws + 152043520);
  unsigned* flags = (unsigned*)(ws + 17825792);  // overlays dead X during scan

  float* outp = (float*)d_out;
  float* hfin = outp + (size_t)M_ * H_;
  float* cfin = hfin + (size_t)B_ * H_;

  zero_init<<<128, 256, 0, stream>>>((uint4*)hb0);
  transpose_cast<<<dim3(128, 32), 256, 0, stream>>>(Wi, WiT);
  transpose_cast<<<dim3(128, 32), 256, 0, stream>>>(Wh, WhT);
  gather_cast<<<32768, 256, 0, stream>>>(inp, emb, X);
  gemm_xw<<<16384, 256, 0, stream>>>(X, WiT, bias, XW2);
  zero_flags<<<4, 256, 0, stream>>>(flags);   // X is dead from here on
  lstm_scan<<<256, 512, 0, stream>>>(WhT, XW2, hb0, hb1, outp, hfin, cfin, flags);
}

// Round 10
// 1922.801 us; speedup vs baseline: 4.6131x; 1.0853x over previous
//
#include <hip/hip_runtime.h>
#include <hip/hip_bf16.h>
#include <stdint.h>

// EncoderFLAX: x = emb[inputs]; xW = x@Wi + b; LSTM scan over S with Wh.
// B=256 S=256 V=32000 E=1024 H=1024. Outputs: [B,S,H] fp32, h [B,H], c [B,H].
//
// Round 10 = round 9 + split-K wave pairs (main change):
//   wave = (gate wg, K-half kh). Each wave computes 32 cols x 512 K with
//   W[2][16] register-resident (same 128 VGPR as before) -> each As read
//   feeds 4 MFMAs (was 2): per-block LDS A-read 512KB -> 256KB per step
//   (the r9 postmortem's dominant term). Cross-pair reduce: kh1 writes
//   partials to zs, barrier, kh0 adds own partials and finalizes.
// Frozen: XCD-local groups (HW_REG_XCC_ID + slot counter), sc0-only h
// exchange through own L2, agent-atomic flags at MALL, permuted XW2,
// reg-staged swizzled As staging, cell in fp32 with c in registers.
//
// ws layout (bytes):
//   WiT 0..8388608, WhT ..16777216, hb0 ..17301504, hb1 ..17825792,
//   X ..152043520 (first 4KB reused: [0..511] group flags, [512..519]
//   xcd slot counters — zeroed by zero_flags each launch), XW ..688914432

#define B_ 256
#define S_ 256
#define E_ 1024
#define H_ 1024
#define G_ 4096
#define M_ 65536

typedef float  f32x4  __attribute__((ext_vector_type(4)));
typedef __bf16 bf16x8 __attribute__((ext_vector_type(8)));

#define MFMA16(a, b, c) __builtin_amdgcn_mfma_f32_16x16x32_bf16((a), (b), (c), 0, 0, 0)

__device__ __forceinline__ void gload_lds16(const void* g, void* l) {
  __builtin_amdgcn_global_load_lds(
      (__attribute__((address_space(1))) void*)(g),
      (__attribute__((address_space(3))) void*)(l), 16, 0, 0);
}

__device__ __forceinline__ float sigm(float x) { return 1.f / (1.f + __expf(-x)); }
__device__ __forceinline__ float tanhfast(float x) {
  float e = __expf(-2.f * x);
  return (1.f - e) / (1.f + e);
}
__device__ __forceinline__ float bf_lo(unsigned v) { return __uint_as_float(v << 16); }
__device__ __forceinline__ float bf_hi(unsigned v) { return __uint_as_float(v & 0xffff0000u); }

// ---------------------------------------------------------------- zero init
__global__ __launch_bounds__(256) void zero_init(uint4* h16) {
  int i = blockIdx.x * 256 + threadIdx.x;
  uint4 z; z.x = z.y = z.z = z.w = 0u;
  if (i < 32768) h16[i] = z;            // hb0: 262144 bf16 = 32768 x 16B
}
__global__ __launch_bounds__(256) void zero_flags(unsigned* flags) {
  flags[blockIdx.x * 256 + threadIdx.x] = 0u;   // 1024 dwords (flags+counters)
}

// ------------------------------------------------- transpose+cast [1024][4096]
__global__ __launch_bounds__(256) void transpose_cast(const float* __restrict__ in,
                                                      __bf16* __restrict__ out) {
  __shared__ __bf16 tile[32][33];
  const int c0 = blockIdx.x * 32;
  const int r0 = blockIdx.y * 32;
  const int tx = threadIdx.x & 31, ty = threadIdx.x >> 5;
#pragma unroll
  for (int p = 0; p < 4; ++p) {
    const int rr = ty + p * 8;
    tile[rr][tx] = (__bf16)in[(size_t)(r0 + rr) * G_ + c0 + tx];
  }
  __syncthreads();
#pragma unroll
  for (int p = 0; p < 4; ++p) {
    const int rr = ty + p * 8;
    out[(size_t)(c0 + rr) * E_ + r0 + tx] = tile[tx][rr];
  }
}

// ------------------------------------------------------- embedding gather+cast
union U16b { uint4 v; __bf16 h[8]; };
__global__ __launch_bounds__(256) void gather_cast(const int* __restrict__ idx,
                                                   const float* __restrict__ emb,
                                                   __bf16* __restrict__ X) {
  const size_t gid  = (size_t)blockIdx.x * 256 + threadIdx.x;
  const size_t base = gid * 8;
  const int r = (int)(base >> 10);
  const int e = (int)(base & 1023);
  const int row = idx[r];
  const float4* s = (const float4*)(emb + (size_t)row * E_ + e);
  const float4 v0 = s[0], v1 = s[1];
  U16b u;
  u.h[0] = (__bf16)v0.x; u.h[1] = (__bf16)v0.y; u.h[2] = (__bf16)v0.z; u.h[3] = (__bf16)v0.w;
  u.h[4] = (__bf16)v1.x; u.h[5] = (__bf16)v1.y; u.h[6] = (__bf16)v1.z; u.h[7] = (__bf16)v1.w;
  *(uint4*)(X + base) = u.v;
}

// --------------------------------------------------- xW GEMM (m97 structure)
// Writes XW PERMUTED: elem offset = ((row*32 + cg)*4 + gate)*32 + col_in_cg.
__global__ __launch_bounds__(256) void gemm_xw(const __bf16* __restrict__ X,
                                               const __bf16* __restrict__ WiT,
                                               const float* __restrict__ bias,
                                               __bf16* __restrict__ XW2) {
  __shared__ __bf16 As[128 * 32];
  __shared__ __bf16 Bs[128 * 32];
  __shared__ __bf16 eps[64][136];
  const int tid = threadIdx.x;
  const int lane = tid & 63;
  const int wid = tid >> 6;
  const int bn = blockIdx.x & 31;
  const int bm = blockIdx.x >> 5;
  const int row0 = bm * 128, col0 = bn * 128;
  const int wr = (wid >> 1) * 64, wc = (wid & 1) * 64;
  const int srow = tid >> 2, schunk = tid & 3;
  const char* gA = (const char*)(X + (size_t)(row0 + srow) * E_) + schunk * 16;
  const char* gB = (const char*)(WiT + (size_t)(col0 + srow) * E_) + schunk * 16;
  char* lA = (char*)As + wid * 1024;
  char* lB = (char*)Bs + wid * 1024;
  const int fr = lane & 15, kb = lane >> 4;

  f32x4 acc[4][4] = {};

  for (int kt = 0; kt < 32; ++kt) {
    gload_lds16(gA + kt * 64,              lA);
    gload_lds16(gA + kt * 64 + 64 * 2048,  lA + 4096);
    gload_lds16(gB + kt * 64,              lB);
    gload_lds16(gB + kt * 64 + 64 * 2048,  lB + 4096);
    __syncthreads();
    bf16x8 a[4], b[4];
#pragma unroll
    for (int m = 0; m < 4; ++m)
      a[m] = *(const bf16x8*)((const char*)As + (wr + m * 16 + fr) * 64 + kb * 16);
#pragma unroll
    for (int n = 0; n < 4; ++n)
      b[n] = *(const bf16x8*)((const char*)Bs + (wc + n * 16 + fr) * 64 + kb * 16);
#pragma unroll
    for (int m = 0; m < 4; ++m)
#pragma unroll
      for (int n = 0; n < 4; ++n)
        acc[m][n] = MFMA16(a[m], b[n], acc[m][n]);
    __syncthreads();
  }

  float bv[4];
#pragma unroll
  for (int n = 0; n < 4; ++n) bv[n] = bias[col0 + wc + n * 16 + fr];

  const int gate = col0 >> 10;             // 128-col tile spans one gate
  const int cg0  = (col0 & 1023) >> 5;     // first of 4 col-groups

#pragma unroll
  for (int h = 0; h < 2; ++h) {
    if ((wid >> 1) == h) {
#pragma unroll
      for (int m = 0; m < 4; ++m)
#pragma unroll
        for (int n = 0; n < 4; ++n)
#pragma unroll
          for (int r = 0; r < 4; ++r)
            eps[m * 16 + kb * 4 + r][wc + n * 16 + fr] = (__bf16)(acc[m][n][r] + bv[n]);
    }
    __syncthreads();
    {
      const int row = tid >> 2, ch = tid & 3;
      const int r_m = row0 + h * 64 + row;
      const uint4* s = (const uint4*)&eps[row][ch * 32];
      uint4* d = (uint4*)(XW2 + ((size_t)r_m * 32 + (cg0 + ch)) * 128 + gate * 32);
#pragma unroll
      for (int i = 0; i < 4; ++i) d[i] = s[i];
    }
    __syncthreads();
  }
}

// ----------------------------------------------------- persistent LSTM scan
// 256 blocks (1/CU), 512 threads. Block = 32 batch rows x 32 h-cols.
// Wave = (gate wg, K-half kh): 32 cols x 512 K each, W[2][16] in registers.
// bg group == XCD (runtime-discovered); h exchange through the group's L2.
__global__ __launch_bounds__(512, 2) void lstm_scan(
    const __bf16* __restrict__ WhT, const __bf16* __restrict__ XW2,
    __bf16* __restrict__ hb0, __bf16* __restrict__ hb1,
    float* __restrict__ outp, float* __restrict__ hfin,
    float* __restrict__ cfin, unsigned* __restrict__ flags) {
  __shared__ __bf16 As[32 * 1024];     // 64 KB, XOR-swizzled 16B chunks
  __shared__ float  zs[4][32][34];
  __shared__ int    sgrp[2];
  const int tid = threadIdx.x;
  const int lane = tid & 63;
  const int wid = tid >> 6;

  // ---- runtime XCD grouping: bg = XCC_ID, cg = slot within the XCD ----
  if (tid == 0) {
    unsigned xcd;
    asm volatile("s_getreg_b32 %0, hwreg(HW_REG_XCC_ID)" : "=s"(xcd));
    xcd &= 7u;
    unsigned slot = __hip_atomic_fetch_add(&flags[512 + xcd], 1u,
                                           __ATOMIC_RELAXED, __HIP_MEMORY_SCOPE_AGENT);
    sgrp[0] = (int)xcd;
    sgrp[1] = (int)(slot & 31u);
  }
  __syncthreads();
  const int bg = sgrp[0];
  const int cg = sgrp[1];
  const int b0 = bg * 32;
  const int c0 = cg * 32;
  unsigned* grpflags = flags + bg * 64;        // 32 flags, 2 cachelines/group

  const int wg = wid & 3;      // gate (i,f,g,o)
  const int kh = wid >> 2;     // K half: [kh*512, kh*512+512)
  const int fr = lane & 15, kb = lane >> 4;

  // ---- Wh slice -> registers, once: cols c0..c0+32, K-half kh ----
  bf16x8 W[2][16];
  {
    const __bf16* wbase = WhT + (size_t)(wg * 1024 + c0) * H_ + kh * 512 + kb * 8;
#pragma unroll
    for (int n = 0; n < 2; ++n)
#pragma unroll
      for (int j = 0; j < 16; ++j)
        W[n][j] = *(const bf16x8*)(wbase + (size_t)(n * 16 + fr) * H_ + j * 32);
  }

  const int crow = tid >> 4, ccolb = (tid & 15) * 2;
  const size_t sidx = (size_t)(b0 + crow) * H_ + c0 + ccolb;
  const __bf16* xwrow = XW2 + ((size_t)(b0 + crow) * S_ * 32 + cg) * 128 + ccolb;
  float creg0 = 0.f, creg1 = 0.f;

#pragma unroll 1
  for (int t = 0; t < S_; ++t) {
    const __bf16* hin = (t & 1) ? hb1 : hb0;
    __bf16* hout = (t & 1) ? hb0 : hb1;

    // XW cell inputs for step t (plain cached loads, issued early).
    const __bf16* p = xwrow + (size_t)t * 4096;
    const unsigned xw0 = *(const unsigned*)(p);
    const unsigned xw1 = *(const unsigned*)(p + 32);
    const unsigned xw2 = *(const unsigned*)(p + 64);
    const unsigned xw3 = *(const unsigned*)(p + 96);

    // ---- wait for h(t-1) of OUR bg group (32 same-XCD producers) ----
    if (t > 0) {
      if (tid < 32) {
        const unsigned tgt = (unsigned)t;
        while (__hip_atomic_load(&grpflags[tid], __ATOMIC_RELAXED,
                                 __HIP_MEMORY_SCOPE_AGENT) < tgt)
          __builtin_amdgcn_s_sleep(1);
      }
      __syncthreads();
    }

    // ---- stage h rows [b0,b0+32): sc0-only loads (own-XCD L2 hit) ----
    {
      uint4 sv[8];
#pragma unroll
      for (int i = 0; i < 8; ++i) {
        const int ci = i * 512 + tid;
        const int row = ci >> 7, cch = ci & 127;
        const void* src = (const char*)(hin + (size_t)(b0 + row) * H_) + cch * 16;
        asm volatile("global_load_dwordx4 %0, %1, off sc0"
                     : "=&v"(sv[i]) : "v"(src) : "memory");
      }
      asm volatile("s_waitcnt vmcnt(0)" ::: "memory");
      __builtin_amdgcn_sched_barrier(0);
#pragma unroll
      for (int i = 0; i < 8; ++i) {
        const int ci = i * 512 + tid;
        const int row = ci >> 7, cch = ci & 127;
        *(uint4*)((char*)As + row * 2048 + ((cch ^ (row & 7)) * 16)) = sv[i];
      }
    }
    __syncthreads();

    // ---- MFMA: 32 rows x 32 cols x 512 K per wave; 1 A-read -> 4 MFMA ----
    f32x4 acc[2][2] = {};   // [row-half][col-half]
#pragma unroll
    for (int j = 0; j < 16; ++j) {
      const int ck = kh * 64 + j * 4 + kb;
      bf16x8 alo = *(const bf16x8*)((const char*)As + fr * 2048 +
                                    ((ck ^ (fr & 7)) * 16));
      bf16x8 ahi = *(const bf16x8*)((const char*)As + (16 + fr) * 2048 +
                                    ((ck ^ (fr & 7)) * 16));
      acc[0][0] = MFMA16(alo, W[0][j], acc[0][0]);
      acc[0][1] = MFMA16(alo, W[1][j], acc[0][1]);
      acc[1][0] = MFMA16(ahi, W[0][j], acc[1][0]);
      acc[1][1] = MFMA16(ahi, W[1][j], acc[1][1]);
    }

    // ---- cross-pair reduction: kh1 writes partials, kh0 adds + finalizes ----
    if (kh) {
#pragma unroll
      for (int rh = 0; rh < 2; ++rh)
#pragma unroll
        for (int n = 0; n < 2; ++n)
#pragma unroll
          for (int r = 0; r < 4; ++r)
            zs[wg][rh * 16 + kb * 4 + r][n * 16 + fr] = acc[rh][n][r];
    }
    __syncthreads();
    if (!kh) {
#pragma unroll
      for (int rh = 0; rh < 2; ++rh)
#pragma unroll
        for (int n = 0; n < 2; ++n)
#pragma unroll
          for (int r = 0; r < 4; ++r)
            zs[wg][rh * 16 + kb * 4 + r][n * 16 + fr] += acc[rh][n][r];
    }
    __syncthreads();

    // ---- cell (fp32), c in registers ----
    const float2 zi2 = *(const float2*)&zs[0][crow][ccolb];
    const float2 zf2 = *(const float2*)&zs[1][crow][ccolb];
    const float2 zg2 = *(const float2*)&zs[2][crow][ccolb];
    const float2 zo2 = *(const float2*)&zs[3][crow][ccolb];
    const float zi0 = zi2.x + bf_lo(xw0), zi1 = zi2.y + bf_hi(xw0);
    const float zf0 = zf2.x + bf_lo(xw1), zf1 = zf2.y + bf_hi(xw1);
    const float zg0 = zg2.x + bf_lo(xw2), zg1 = zg2.y + bf_hi(xw2);
    const float zo0 = zo2.x + bf_lo(xw3), zo1 = zo2.y + bf_hi(xw3);
    const float cv0 = sigm(zf0) * creg0 + sigm(zi0) * tanhfast(zg0);
    const float cv1 = sigm(zf1) * creg1 + sigm(zi1) * tanhfast(zg1);
    creg0 = cv0; creg1 = cv1;
    const float hv0 = sigm(zo0) * tanhfast(cv0);
    const float hv1 = sigm(zo1) * tanhfast(cv1);

    union { __bf16 h[2]; unsigned u; } up;
    up.h[0] = (__bf16)hv0; up.h[1] = (__bf16)hv1;
    float2 o2; o2.x = hv0; o2.y = hv1;

    // h store: sc0-only -> lands in our XCD's L2 (consumers are same-XCD)
    {
      void* dst = (void*)(hout + sidx);
      asm volatile("global_store_dword %0, %1, off sc0"
                   :: "v"(dst), "v"(up.u) : "memory");
    }

    if (t == S_ - 1) {
      *(float2*)(outp + ((size_t)(b0 + crow) * S_ + t) * H_ + c0 + ccolb) = o2;
      float2 c2; c2.x = cv0; c2.y = cv1;
      *(float2*)(hfin + sidx) = o2;
      *(float2*)(cfin + sidx) = c2;
    } else {
      asm volatile("s_waitcnt vmcnt(0)" ::: "memory");   // h committed to L2
      __builtin_amdgcn_s_barrier();
      if (tid == 0)
        __hip_atomic_store(&grpflags[cg], (unsigned)(t + 1),
                           __ATOMIC_RELAXED, __HIP_MEMORY_SCOPE_AGENT);
      // outp store AFTER the flag: a full step of slack to drain
      *(float2*)(outp + ((size_t)(b0 + crow) * S_ + t) * H_ + c0 + ccolb) = o2;
    }
  }
}

// ----------------------------------------------------------------- launcher
extern "C" void kernel_launch(void* const* d_in, const int* in_sizes, int n_in,
                              void* d_out, int out_size, void* d_ws, size_t ws_size,
                              hipStream_t stream) {
  const int*   inp  = (const int*)d_in[0];
  const float* emb  = (const float*)d_in[1];
  const float* Wi   = (const float*)d_in[2];
  const float* Wh   = (const float*)d_in[3];
  const float* bias = (const float*)d_in[4];

  char* ws = (char*)d_ws;
  __bf16* WiT = (__bf16*)(ws);
  __bf16* WhT = (__bf16*)(ws + 8388608);
  __bf16* hb0 = (__bf16*)(ws + 16777216);
  __bf16* hb1 = (__bf16*)(ws + 17301504);
  __bf16* X   = (__bf16*)(ws + 17825792);
  __bf16* XW2 = (__bf16*)(ws + 152043520);
  unsigned* flags = (unsigned*)(ws + 17825792);  // overlays dead X during scan

  float* outp = (float*)d_out;
  float* hfin = outp + (size_t)M_ * H_;
  float* cfin = hfin + (size_t)B_ * H_;

  zero_init<<<128, 256, 0, stream>>>((uint4*)hb0);
  transpose_cast<<<dim3(128, 32), 256, 0, stream>>>(Wi, WiT);
  transpose_cast<<<dim3(128, 32), 256, 0, stream>>>(Wh, WhT);
  gather_cast<<<32768, 256, 0, stream>>>(inp, emb, X);
  gemm_xw<<<16384, 256, 0, stream>>>(X, WiT, bias, XW2);
  zero_flags<<<4, 256, 0, stream>>>(flags);   // X is dead from here on
  lstm_scan<<<256, 512, 0, stream>>>(WhT, XW2, hb0, hb1, outp, hfin, cfin, flags);
}